// Round 1
// baseline (3200.510 us; speedup 1.0000x reference)
//
#include <hip/hip_runtime.h>

#ifndef BATCH
#define BATCH 16
#endif

// ---------------------------------------------------------------------------
// FPS: one block per batch. Coordinates cached in registers + LDS.
// Matches jnp semantics: dist=min(dist, ||p - p_far||^2), argmax first-index.
// ---------------------------------------------------------------------------
template<int N, int NPOINT, int BLOCK>
__global__ __launch_bounds__(BLOCK)
void fps_kernel(const float* __restrict__ xyz, float* __restrict__ out_xyz)
{
#pragma clang fp contract(off)
    constexpr int P = N / BLOCK;
    constexpr int NW = BLOCK / 64;
    __shared__ float sx[N], sy[N], sz[N];
    __shared__ float rv[NW];
    __shared__ int   ri[NW];
    const int b = blockIdx.x, t = threadIdx.x;
    const float* xb = xyz + (size_t)b * N * 3;
    float px[P], py[P], pz[P], dist[P];
#pragma unroll
    for (int j = 0; j < P; ++j) {
        const int i = t + j * BLOCK;
        const float x = xb[i*3+0], y = xb[i*3+1], z = xb[i*3+2];
        sx[i] = x; sy[i] = y; sz[i] = z;
        px[j] = x; py[j] = y; pz[j] = z;
        dist[j] = 1e10f;
    }
    __syncthreads();
    int far = 0;
    if (t == 0) {
        out_xyz[(size_t)b*NPOINT*3 + 0] = sx[0];
        out_xyz[(size_t)b*NPOINT*3 + 1] = sy[0];
        out_xyz[(size_t)b*NPOINT*3 + 2] = sz[0];
    }
    for (int s = 1; s < NPOINT; ++s) {
        const float fx = sx[far], fy = sy[far], fz = sz[far];
        float bestv = -1.f; int besti = 0x7fffffff;
#pragma unroll
        for (int j = 0; j < P; ++j) {
            const float dx = px[j]-fx, dy = py[j]-fy, dz = pz[j]-fz;
            const float d = (dx*dx + dy*dy) + dz*dz;
            const float nd = fminf(dist[j], d);
            dist[j] = nd;
            const int i = t + j * BLOCK;
            if (nd > bestv) { bestv = nd; besti = i; }  // ascending i within thread
        }
        // wave reduce: max value, tie -> min index
#pragma unroll
        for (int m = 32; m >= 1; m >>= 1) {
            const float ov = __shfl_xor(bestv, m);
            const int   oi = __shfl_xor(besti, m);
            if (ov > bestv || (ov == bestv && oi < besti)) { bestv = ov; besti = oi; }
        }
        if ((t & 63) == 0) { rv[t >> 6] = bestv; ri[t >> 6] = besti; }
        __syncthreads();
        bestv = rv[0]; besti = ri[0];
#pragma unroll
        for (int w = 1; w < NW; ++w) {
            const float ov = rv[w]; const int oi = ri[w];
            if (ov > bestv || (ov == bestv && oi < besti)) { bestv = ov; besti = oi; }
        }
        far = besti;
        if (t == 0) {
            out_xyz[((size_t)b*NPOINT + s)*3 + 0] = sx[far];
            out_xyz[((size_t)b*NPOINT + s)*3 + 1] = sy[far];
            out_xyz[((size_t)b*NPOINT + s)*3 + 2] = sz[far];
        }
        __syncthreads();
    }
}

// ---------------------------------------------------------------------------
// Ball query: one wave per query point. First K in-radius indices (ascending),
// misses padded with first hit.
// ---------------------------------------------------------------------------
template<int N, int S, int K>
__global__ __launch_bounds__(256)
void ballq_kernel(const float* __restrict__ xyz, const float* __restrict__ nxyz,
                  int* __restrict__ idx, const float r2)
{
#pragma clang fp contract(off)
    const int gw = (blockIdx.x * 256 + threadIdx.x) >> 6;  // global wave = query
    const int lane = threadIdx.x & 63;
    const int b = gw / S, s = gw % S;
    const float* xb = xyz + (size_t)b * N * 3;
    const float qx = nxyz[((size_t)b*S + s)*3 + 0];
    const float qy = nxyz[((size_t)b*S + s)*3 + 1];
    const float qz = nxyz[((size_t)b*S + s)*3 + 2];
    int* op = idx + ((size_t)b*S + s) * K;
    int base = 0, first = -1;
    for (int c = 0; c < N; c += 64) {
        const int i = c + lane;
        const float dx = xb[i*3+0]-qx, dy = xb[i*3+1]-qy, dz = xb[i*3+2]-qz;
        const float d = (dx*dx + dy*dy) + dz*dz;
        const bool hit = !(d > r2);
        const unsigned long long m = __ballot(hit);
        if (first < 0 && m) first = c + __builtin_ctzll(m);
        const int pos = base + __popcll(m & ((1ull << lane) - 1ull));
        if (hit && pos < K) op[pos] = i;
        base += __popcll(m);
        if (base >= K) break;
    }
    if (base < K && lane >= base && lane < K) op[lane] = first;
}

// ---------------------------------------------------------------------------
// SA1 fused MLP+maxpool. K=32 -> 2 groups per wave (half-wave each).
// Weights are wave-uniform -> scalar (s_load) operands. Hidden layer bounced
// through a lane-private LDS row (stride 65 -> conflict-free).
// ---------------------------------------------------------------------------
__global__ __launch_bounds__(256)
void sa1_kernel(const float* __restrict__ xyz, const float* __restrict__ nxyz,
                const int* __restrict__ idx,
                const float* __restrict__ W0, const float* __restrict__ B0,
                const float* __restrict__ W1, const float* __restrict__ B1,
                const float* __restrict__ W2, const float* __restrict__ B2,
                float* __restrict__ out)
{
    __shared__ float hrow[256][65];
    const int tid = threadIdx.x;
    const int lane = tid & 63, wave = tid >> 6;
    const int g = blockIdx.x * 8 + wave * 2 + (lane >> 5);  // group in [0, B*512)
    const int b = g >> 9;
    const int k = lane & 31;
    const int i = idx[((size_t)g << 5) + k];
    const float* p = xyz + ((size_t)b*4096 + i) * 3;
    const float* c = nxyz + (size_t)g * 3;
    const float f0 = p[0]-c[0], f1 = p[1]-c[1], f2 = p[2]-c[2];
    float h[64];
#pragma unroll
    for (int oc = 0; oc < 64; ++oc)
        h[oc] = fmaxf(B0[oc] + f0*W0[oc*3+0] + f1*W0[oc*3+1] + f2*W0[oc*3+2], 0.f);
    for (int oc = 0; oc < 64; ++oc) {
        const float* wr = W1 + oc * 64;
        float a0=0.f, a1=0.f, a2=0.f, a3=0.f;
#pragma unroll
        for (int ci = 0; ci < 64; ci += 4) {
            a0 += h[ci+0]*wr[ci+0]; a1 += h[ci+1]*wr[ci+1];
            a2 += h[ci+2]*wr[ci+2]; a3 += h[ci+3]*wr[ci+3];
        }
        hrow[tid][oc] = fmaxf(((a0+a1)+(a2+a3)) + B1[oc], 0.f);
    }
#pragma unroll
    for (int ci = 0; ci < 64; ++ci) h[ci] = hrow[tid][ci];
    float* orow = out + (size_t)g * 128;
    for (int oc = 0; oc < 128; ++oc) {
        const float* wr = W2 + oc * 64;
        float a0=0.f, a1=0.f, a2=0.f, a3=0.f;
#pragma unroll
        for (int ci = 0; ci < 64; ci += 4) {
            a0 += h[ci+0]*wr[ci+0]; a1 += h[ci+1]*wr[ci+1];
            a2 += h[ci+2]*wr[ci+2]; a3 += h[ci+3]*wr[ci+3];
        }
        float v = fmaxf(((a0+a1)+(a2+a3)) + B2[oc], 0.f);
        v = fmaxf(v, __shfl_xor(v, 1));
        v = fmaxf(v, __shfl_xor(v, 2));
        v = fmaxf(v, __shfl_xor(v, 4));
        v = fmaxf(v, __shfl_xor(v, 8));
        v = fmaxf(v, __shfl_xor(v, 16));
        if ((lane & 31) == 0) orow[oc] = v;
    }
}

// ---------------------------------------------------------------------------
// SA2 fused MLP+maxpool. K=64 -> one group per wave (lane = sample).
// in[131] in registers; hidden layers bounced via lane-private LDS rows.
// ---------------------------------------------------------------------------
__global__ __launch_bounds__(128)
void sa2_kernel(const float* __restrict__ l1xyz, const float* __restrict__ l1pts,
                const float* __restrict__ nxyz, const int* __restrict__ idx,
                const float* __restrict__ W0, const float* __restrict__ B0,
                const float* __restrict__ W1, const float* __restrict__ B1,
                const float* __restrict__ W2, const float* __restrict__ B2,
                float* __restrict__ out)
{
    __shared__ float hrow[128][129];
    const int tid = threadIdx.x;
    const int lane = tid & 63, wave = tid >> 6;
    const int g = blockIdx.x * 2 + wave;          // group in [0, B*128)
    const int b = g >> 7;
    const int i = idx[(size_t)g * 64 + lane];
    const float* p = l1xyz + ((size_t)b*512 + i) * 3;
    const float* c = nxyz + (size_t)g * 3;
    float fin[131];
    fin[0] = p[0]-c[0]; fin[1] = p[1]-c[1]; fin[2] = p[2]-c[2];
    const float4* pr = (const float4*)(l1pts + ((size_t)b*512 + i) * 128);
#pragma unroll
    for (int j = 0; j < 32; ++j) {
        const float4 v = pr[j];
        fin[3+4*j] = v.x; fin[4+4*j] = v.y; fin[5+4*j] = v.z; fin[6+4*j] = v.w;
    }
    // L1: 131 -> 128
    for (int oc = 0; oc < 128; ++oc) {
        const float* wr = W0 + oc * 131;
        float a0=0.f, a1=0.f, a2=0.f, a3=0.f;
#pragma unroll
        for (int ci = 0; ci < 128; ci += 4) {
            a0 += fin[ci+0]*wr[ci+0]; a1 += fin[ci+1]*wr[ci+1];
            a2 += fin[ci+2]*wr[ci+2]; a3 += fin[ci+3]*wr[ci+3];
        }
        a0 += fin[128]*wr[128]; a1 += fin[129]*wr[129]; a2 += fin[130]*wr[130];
        hrow[tid][oc] = fmaxf(((a0+a1)+(a2+a3)) + B0[oc], 0.f);
    }
    float h[128];
#pragma unroll
    for (int ci = 0; ci < 128; ++ci) h[ci] = hrow[tid][ci];
    // L2: 128 -> 128
    for (int oc = 0; oc < 128; ++oc) {
        const float* wr = W1 + oc * 128;
        float a0=0.f, a1=0.f, a2=0.f, a3=0.f;
#pragma unroll
        for (int ci = 0; ci < 128; ci += 4) {
            a0 += h[ci+0]*wr[ci+0]; a1 += h[ci+1]*wr[ci+1];
            a2 += h[ci+2]*wr[ci+2]; a3 += h[ci+3]*wr[ci+3];
        }
        hrow[tid][oc] = fmaxf(((a0+a1)+(a2+a3)) + B1[oc], 0.f);
    }
#pragma unroll
    for (int ci = 0; ci < 128; ++ci) h[ci] = hrow[tid][ci];
    // L3: 128 -> 256 with max over the 64 lanes (=K)
    float* orow = out + (size_t)g * 256;
    for (int oc = 0; oc < 256; ++oc) {
        const float* wr = W2 + oc * 128;
        float a0=0.f, a1=0.f, a2=0.f, a3=0.f;
#pragma unroll
        for (int ci = 0; ci < 128; ci += 4) {
            a0 += h[ci+0]*wr[ci+0]; a1 += h[ci+1]*wr[ci+1];
            a2 += h[ci+2]*wr[ci+2]; a3 += h[ci+3]*wr[ci+3];
        }
        float v = fmaxf(((a0+a1)+(a2+a3)) + B2[oc], 0.f);
        v = fmaxf(v, __shfl_xor(v, 32));
        v = fmaxf(v, __shfl_xor(v, 16));
        v = fmaxf(v, __shfl_xor(v, 8));
        v = fmaxf(v, __shfl_xor(v, 4));
        v = fmaxf(v, __shfl_xor(v, 2));
        v = fmaxf(v, __shfl_xor(v, 1));
        if (lane == 0) orow[oc] = v;
    }
}

// ---------------------------------------------------------------------------
// SA3 layers as row-GEMM: out[row][oc] = relu(bias + in[row][:] . W[oc][:]).
// 64 rows staged transposed in LDS per 128-ci chunk; wave owns 16 oc.
// ---------------------------------------------------------------------------
template<int CIN, int COUT, bool CONCAT3>
__global__ __launch_bounds__(256)
void mlp_gemm_kernel(const float* __restrict__ inA, const float* __restrict__ inB,
                     const float* __restrict__ W, const float* __restrict__ Bb,
                     float* __restrict__ out)
{
    __shared__ float sft[128][65];
    const int tid = threadIdx.x, lane = tid & 63, wave = tid >> 6;
    const int row0 = blockIdx.x * 64;
    const int myoc0 = blockIdx.y * 64 + wave * 16;
    float acc[16];
#pragma unroll
    for (int j = 0; j < 16; ++j) acc[j] = 0.f;
    for (int c0 = 0; c0 < CIN; c0 += 128) {
        const int csz = (CIN - c0 < 128) ? (CIN - c0) : 128;
        for (int r = wave; r < 64; r += 4) {
            const int row = row0 + r;
            for (int cl = lane; cl < csz; cl += 64) {
                const int cig = c0 + cl;
                float v;
                if (CONCAT3)
                    v = (cig < 3) ? inA[(size_t)row*3 + cig]
                                  : inB[(size_t)row*(CIN-3) + (cig - 3)];
                else
                    v = inA[(size_t)row*CIN + cig];
                sft[cl][r] = v;
            }
        }
        __syncthreads();
        if (csz == 128) {
#pragma unroll 4
            for (int ci = 0; ci < 128; ++ci) {
                const float f = sft[ci][lane];
                const float* wp = W + (size_t)myoc0*CIN + c0 + ci;
#pragma unroll
                for (int j = 0; j < 16; ++j) acc[j] += f * wp[(size_t)j*CIN];
            }
        } else {
            for (int ci = 0; ci < csz; ++ci) {
                const float f = sft[ci][lane];
                const float* wp = W + (size_t)myoc0*CIN + c0 + ci;
#pragma unroll
                for (int j = 0; j < 16; ++j) acc[j] += f * wp[(size_t)j*CIN];
            }
        }
        __syncthreads();
    }
    const int row = row0 + lane;
#pragma unroll
    for (int j = 0; j < 16; ++j)
        out[(size_t)row*COUT + myoc0 + j] = fmaxf(acc[j] + Bb[myoc0 + j], 0.f);
}

// max over K=128 rows per batch: h3 [16*128][1024] -> g [16][1024]
__global__ __launch_bounds__(256)
void maxpool_kernel(const float* __restrict__ h3, float* __restrict__ g)
{
    const int i = blockIdx.x * 256 + threadIdx.x;   // 16*1024
    const int b = i >> 10, c = i & 1023;
    const float* p = h3 + (size_t)b * 128 * 1024 + c;
    float m = p[0];
    for (int k = 1; k < 128; ++k) m = fmaxf(m, p[(size_t)k * 1024]);
    g[i] = m;
}

// y[b][o] = fb[o] + g[b][:] . fw[o][:]; one wave per output
__global__ __launch_bounds__(256)
void fc_kernel(const float* __restrict__ g, const float* __restrict__ fw,
               const float* __restrict__ fb, float* __restrict__ y)
{
    const int gw = (blockIdx.x * 256 + threadIdx.x) >> 6;  // 0..16383
    const int lane = threadIdx.x & 63;
    const int b = gw >> 10, o = gw & 1023;
    const float4* gv = (const float4*)(g + (size_t)b * 1024);
    const float4* wv = (const float4*)(fw + (size_t)o * 1024);
    float acc = 0.f;
#pragma unroll
    for (int r = 0; r < 4; ++r) {
        const float4 gf = gv[lane + r*64];
        const float4 wf = wv[lane + r*64];
        acc += gf.x*wf.x + gf.y*wf.y + gf.z*wf.z + gf.w*wf.w;
    }
#pragma unroll
    for (int m = 32; m >= 1; m >>= 1) acc += __shfl_xor(acc, m);
    if (lane == 0) y[gw] = acc + fb[o];
}

extern "C" void kernel_launch(void* const* d_in, const int* in_sizes, int n_in,
                              void* d_out, int out_size, void* d_ws, size_t ws_size,
                              hipStream_t stream)
{
    (void)in_sizes; (void)n_in; (void)out_size; (void)ws_size;
    const float* x   = (const float*)d_in[0];
    const float* s1w0 = (const float*)d_in[1];  const float* s1b0 = (const float*)d_in[2];
    const float* s1w1 = (const float*)d_in[3];  const float* s1b1 = (const float*)d_in[4];
    const float* s1w2 = (const float*)d_in[5];  const float* s1b2 = (const float*)d_in[6];
    const float* s2w0 = (const float*)d_in[7];  const float* s2b0 = (const float*)d_in[8];
    const float* s2w1 = (const float*)d_in[9];  const float* s2b1 = (const float*)d_in[10];
    const float* s2w2 = (const float*)d_in[11]; const float* s2b2 = (const float*)d_in[12];
    const float* s3w0 = (const float*)d_in[13]; const float* s3b0 = (const float*)d_in[14];
    const float* s3w1 = (const float*)d_in[15]; const float* s3b1 = (const float*)d_in[16];
    const float* s3w2 = (const float*)d_in[17]; const float* s3b2 = (const float*)d_in[18];
    const float* fw  = (const float*)d_in[19]; const float* fb  = (const float*)d_in[20];
    float* y = (float*)d_out;

    char* ws = (char*)d_ws;
    float* l1_xyz = (float*)(ws + 0);          // 16*512*3
    int*   idx1   = (int*)  (ws + 98304);      // 16*512*32
    float* l1_pts = (float*)(ws + 1146880);    // 16*512*128
    float* l2_xyz = (float*)(ws + 5341184);    // 16*128*3
    int*   idx2   = (int*)  (ws + 5365760);    // 16*128*64
    float* l2_pts = (float*)(ws + 5890048);    // 16*128*256
    float* h1     = (float*)(ws + 7987200);    // 2048*256
    float* h2     = (float*)(ws + 10084352);   // 2048*512
    float* h3     = (float*)(ws + 14278656);   // 2048*1024
    float* g      = (float*)(ws + 22667264);   // 16*1024

    const float r2_1 = (float)(0.2 * 0.2);     // match JAX weak-type f64->f32 cast
    const float r2_2 = (float)(0.4 * 0.4);

    fps_kernel<4096, 512, 512><<<BATCH, 512, 0, stream>>>(x, l1_xyz);
    ballq_kernel<4096, 512, 32><<<(BATCH*512)/4, 256, 0, stream>>>(x, l1_xyz, idx1, r2_1);
    sa1_kernel<<<(BATCH*512)/8, 256, 0, stream>>>(x, l1_xyz, idx1,
        s1w0, s1b0, s1w1, s1b1, s1w2, s1b2, l1_pts);
    fps_kernel<512, 128, 256><<<BATCH, 256, 0, stream>>>(l1_xyz, l2_xyz);
    ballq_kernel<512, 128, 64><<<(BATCH*128)/4, 256, 0, stream>>>(l1_xyz, l2_xyz, idx2, r2_2);
    sa2_kernel<<<(BATCH*128)/2, 128, 0, stream>>>(l1_xyz, l1_pts, l2_xyz, idx2,
        s2w0, s2b0, s2w1, s2b1, s2w2, s2b2, l2_pts);
    mlp_gemm_kernel<259, 256, true ><<<dim3(32, 4),  256, 0, stream>>>(l2_xyz, l2_pts, s3w0, s3b0, h1);
    mlp_gemm_kernel<256, 512, false><<<dim3(32, 8),  256, 0, stream>>>(h1, nullptr, s3w1, s3b1, h2);
    mlp_gemm_kernel<512, 1024,false><<<dim3(32, 16), 256, 0, stream>>>(h2, nullptr, s3w2, s3b2, h3);
    maxpool_kernel<<<(BATCH*1024)/256, 256, 0, stream>>>(h3, g);
    fc_kernel<<<(BATCH*1024)/4, 256, 0, stream>>>(g, fw, fb, y);
}

// Round 2
// 2477.059 us; speedup vs baseline: 1.2921x; 1.2921x over previous
//
#include <hip/hip_runtime.h>

#ifndef BATCH
#define BATCH 16
#endif

// ---------------------------------------------------------------------------
// FPS: one block per batch. Coordinates cached in registers + LDS.
// Matches jnp semantics: dist=min(dist, ||p - p_far||^2), argmax first-index.
// ---------------------------------------------------------------------------
template<int N, int NPOINT, int BLOCK>
__global__ __launch_bounds__(BLOCK)
void fps_kernel(const float* __restrict__ xyz, float* __restrict__ out_xyz)
{
#pragma clang fp contract(off)
    constexpr int P = N / BLOCK;
    constexpr int NW = BLOCK / 64;
    __shared__ float sx[N], sy[N], sz[N];
    __shared__ float rv[NW];
    __shared__ int   ri[NW];
    const int b = blockIdx.x, t = threadIdx.x;
    const float* xb = xyz + (size_t)b * N * 3;
    float px[P], py[P], pz[P], dist[P];
#pragma unroll
    for (int j = 0; j < P; ++j) {
        const int i = t + j * BLOCK;
        const float x = xb[i*3+0], y = xb[i*3+1], z = xb[i*3+2];
        sx[i] = x; sy[i] = y; sz[i] = z;
        px[j] = x; py[j] = y; pz[j] = z;
        dist[j] = 1e10f;
    }
    __syncthreads();
    int far = 0;
    if (t == 0) {
        out_xyz[(size_t)b*NPOINT*3 + 0] = sx[0];
        out_xyz[(size_t)b*NPOINT*3 + 1] = sy[0];
        out_xyz[(size_t)b*NPOINT*3 + 2] = sz[0];
    }
    for (int s = 1; s < NPOINT; ++s) {
        const float fx = sx[far], fy = sy[far], fz = sz[far];
        float bestv = -1.f; int besti = 0x7fffffff;
#pragma unroll
        for (int j = 0; j < P; ++j) {
            const float dx = px[j]-fx, dy = py[j]-fy, dz = pz[j]-fz;
            const float d = (dx*dx + dy*dy) + dz*dz;
            const float nd = fminf(dist[j], d);
            dist[j] = nd;
            const int i = t + j * BLOCK;
            if (nd > bestv) { bestv = nd; besti = i; }  // ascending i within thread
        }
        // wave reduce: max value, tie -> min index
#pragma unroll
        for (int m = 32; m >= 1; m >>= 1) {
            const float ov = __shfl_xor(bestv, m);
            const int   oi = __shfl_xor(besti, m);
            if (ov > bestv || (ov == bestv && oi < besti)) { bestv = ov; besti = oi; }
        }
        if ((t & 63) == 0) { rv[t >> 6] = bestv; ri[t >> 6] = besti; }
        __syncthreads();
        bestv = rv[0]; besti = ri[0];
#pragma unroll
        for (int w = 1; w < NW; ++w) {
            const float ov = rv[w]; const int oi = ri[w];
            if (ov > bestv || (ov == bestv && oi < besti)) { bestv = ov; besti = oi; }
        }
        far = besti;
        if (t == 0) {
            out_xyz[((size_t)b*NPOINT + s)*3 + 0] = sx[far];
            out_xyz[((size_t)b*NPOINT + s)*3 + 1] = sy[far];
            out_xyz[((size_t)b*NPOINT + s)*3 + 2] = sz[far];
        }
        __syncthreads();
    }
}

// ---------------------------------------------------------------------------
// Ball query: one wave per query point. First K in-radius indices (ascending),
// misses padded with first hit.
// ---------------------------------------------------------------------------
template<int N, int S, int K>
__global__ __launch_bounds__(256)
void ballq_kernel(const float* __restrict__ xyz, const float* __restrict__ nxyz,
                  int* __restrict__ idx, const float r2)
{
#pragma clang fp contract(off)
    const int gw = (blockIdx.x * 256 + threadIdx.x) >> 6;  // global wave = query
    const int lane = threadIdx.x & 63;
    const int b = gw / S, s = gw % S;
    const float* xb = xyz + (size_t)b * N * 3;
    const float qx = nxyz[((size_t)b*S + s)*3 + 0];
    const float qy = nxyz[((size_t)b*S + s)*3 + 1];
    const float qz = nxyz[((size_t)b*S + s)*3 + 2];
    int* op = idx + ((size_t)b*S + s) * K;
    int base = 0, first = -1;
    for (int c = 0; c < N; c += 64) {
        const int i = c + lane;
        const float dx = xb[i*3+0]-qx, dy = xb[i*3+1]-qy, dz = xb[i*3+2]-qz;
        const float d = (dx*dx + dy*dy) + dz*dz;
        const bool hit = !(d > r2);
        const unsigned long long m = __ballot(hit);
        if (first < 0 && m) first = c + __builtin_ctzll(m);
        const int pos = base + __popcll(m & ((1ull << lane) - 1ull));
        if (hit && pos < K) op[pos] = i;
        base += __popcll(m);
        if (base >= K) break;
    }
    if (base < K && lane >= base && lane < K) op[lane] = first;
}

// ---------------------------------------------------------------------------
// SA1 fully fused: block = 256 thr (4 waves) owns 64 rows (2 groups of K=32).
// Layer activations live in oc-major LDS [ch][row] (conflict-free), weights
// are wave-uniform scalar loads. Zero global intermediates.
// ---------------------------------------------------------------------------
__global__ __launch_bounds__(256)
void sa1_fused(const float* __restrict__ xyz, const float* __restrict__ nxyz,
               const int* __restrict__ idx,
               const float* __restrict__ W0, const float* __restrict__ B0,
               const float* __restrict__ W1, const float* __restrict__ B1,
               const float* __restrict__ W2, const float* __restrict__ B2,
               float* __restrict__ out)
{
    __shared__ float bufA[64][64];   // h1 (oc-major)
    __shared__ float bufB[64][64];   // h2 (oc-major)
    const int tid = threadIdx.x, lane = tid & 63, wave = tid >> 6;
    const int row0 = blockIdx.x * 64;
    const int myrow = row0 + lane;
    const int g = myrow >> 5, b = g >> 9;
    const int i = idx[myrow];
    const float* p = xyz + ((size_t)b*4096 + i) * 3;
    const float f0 = p[0] - nxyz[(size_t)g*3 + 0];
    const float f1 = p[1] - nxyz[(size_t)g*3 + 1];
    const float f2 = p[2] - nxyz[(size_t)g*3 + 2];
    const int oc0 = wave * 16;
    float acc[16];
    // L1: 3 -> 64
#pragma unroll
    for (int j = 0; j < 16; ++j) {
        const float* w = W0 + (size_t)(oc0 + j) * 3;
        bufA[oc0 + j][lane] = fmaxf(f0*w[0] + f1*w[1] + f2*w[2] + B0[oc0 + j], 0.f);
    }
    __syncthreads();
    // L2: 64 -> 64
#pragma unroll
    for (int j = 0; j < 16; ++j) acc[j] = 0.f;
#pragma unroll 4
    for (int ci = 0; ci < 64; ++ci) {
        const float f = bufA[ci][lane];
        const float* wp = W1 + (size_t)oc0*64 + ci;
#pragma unroll
        for (int j = 0; j < 16; ++j) acc[j] += f * wp[(size_t)j*64];
    }
#pragma unroll
    for (int j = 0; j < 16; ++j)
        bufB[oc0 + j][lane] = fmaxf(acc[j] + B1[oc0 + j], 0.f);
    __syncthreads();
    // L3: 64 -> 128, fused maxpool over K=32 (half-wave reduce)
    for (int p2 = 0; p2 < 2; ++p2) {
        const int oc = p2*64 + oc0;
#pragma unroll
        for (int j = 0; j < 16; ++j) acc[j] = 0.f;
#pragma unroll 4
        for (int ci = 0; ci < 64; ++ci) {
            const float f = bufB[ci][lane];
            const float* wp = W2 + (size_t)oc*64 + ci;
#pragma unroll
            for (int j = 0; j < 16; ++j) acc[j] += f * wp[(size_t)j*64];
        }
#pragma unroll
        for (int j = 0; j < 16; ++j) {
            float v = fmaxf(acc[j] + B2[oc + j], 0.f);
            v = fmaxf(v, __shfl_xor(v, 1));
            v = fmaxf(v, __shfl_xor(v, 2));
            v = fmaxf(v, __shfl_xor(v, 4));
            v = fmaxf(v, __shfl_xor(v, 8));
            v = fmaxf(v, __shfl_xor(v, 16));
            if ((lane & 31) == 0)
                out[(size_t)((row0 + lane) >> 5) * 128 + oc + j] = v;
        }
    }
}

// ---------------------------------------------------------------------------
// SA2 fully fused: block = 512 thr (8 waves) owns 64 rows (1 group, K=64).
// Gathered input in row-major LDS with XOR-31 column swizzle (conflict-free
// transpose read); hidden layers ping-pong oc-major. LDS = exactly 64 KB.
// ---------------------------------------------------------------------------
__global__ __launch_bounds__(512)
void sa2_fused(const float* __restrict__ l1xyz, const float* __restrict__ l1pts,
               const float* __restrict__ nxyz, const int* __restrict__ idx,
               const float* __restrict__ W0, const float* __restrict__ B0,
               const float* __restrict__ W1, const float* __restrict__ B1,
               const float* __restrict__ W2, const float* __restrict__ B2,
               float* __restrict__ out)
{
    __shared__ float bufA[64][128];  // gathered feats, [r][c ^ (r&31)]; reused as h2
    __shared__ float bufH[128][64];  // h1 (oc-major)
    const int tid = threadIdx.x, lane = tid & 63, wave = tid >> 6;  // 8 waves
    const int gblk = blockIdx.x;               // group id
    const int row0 = gblk * 64;
    const int b = gblk >> 7;
    // per-lane own-row xyz diff (lane = row)
    const int myi = idx[row0 + lane];
    const float* pc = l1xyz + ((size_t)b*512 + myi) * 3;
    const float f0 = pc[0] - nxyz[(size_t)gblk*3 + 0];
    const float f1 = pc[1] - nxyz[(size_t)gblk*3 + 1];
    const float f2 = pc[2] - nxyz[(size_t)gblk*3 + 2];
    // stage 128 feature channels per row, coalesced, swizzled
    for (int r = wave; r < 64; r += 8) {
        const int i2 = idx[row0 + r];
        const float* src = l1pts + ((size_t)b*512 + i2) * 128;
        const int rs = r & 31;
        bufA[r][lane ^ rs]        = src[lane];
        bufA[r][(lane + 64) ^ rs] = src[lane + 64];
    }
    __syncthreads();
    const int oc0 = wave * 16;   // 8 waves x 16 = 128 ocs per pass
    const int sw = lane & 31;
    float acc[16];
    // L1: 131 -> 128
#pragma unroll
    for (int j = 0; j < 16; ++j) {
        const float* w = W0 + (size_t)(oc0 + j) * 131;
        acc[j] = f0*w[0] + f1*w[1] + f2*w[2];
    }
#pragma unroll 4
    for (int ci = 0; ci < 128; ++ci) {
        const float f = bufA[lane][ci ^ sw];
        const float* wp = W0 + (size_t)oc0*131 + 3 + ci;
#pragma unroll
        for (int j = 0; j < 16; ++j) acc[j] += f * wp[(size_t)j*131];
    }
#pragma unroll
    for (int j = 0; j < 16; ++j)
        bufH[oc0 + j][lane] = fmaxf(acc[j] + B0[oc0 + j], 0.f);
    __syncthreads();
    // L2: 128 -> 128 ; output overwrites bufA region as oc-major [128][64]
    float (*bufG)[64] = (float(*)[64])bufA;
#pragma unroll
    for (int j = 0; j < 16; ++j) acc[j] = 0.f;
#pragma unroll 4
    for (int ci = 0; ci < 128; ++ci) {
        const float f = bufH[ci][lane];
        const float* wp = W1 + (size_t)oc0*128 + ci;
#pragma unroll
        for (int j = 0; j < 16; ++j) acc[j] += f * wp[(size_t)j*128];
    }
    __syncthreads();   // all L1 reads of bufA done before overwrite
#pragma unroll
    for (int j = 0; j < 16; ++j)
        bufG[oc0 + j][lane] = fmaxf(acc[j] + B1[oc0 + j], 0.f);
    __syncthreads();
    // L3: 128 -> 256 (two oc passes), fused maxpool over K=64 (full wave)
    for (int p2 = 0; p2 < 2; ++p2) {
        const int oc = p2*128 + oc0;
#pragma unroll
        for (int j = 0; j < 16; ++j) acc[j] = 0.f;
#pragma unroll 4
        for (int ci = 0; ci < 128; ++ci) {
            const float f = bufG[ci][lane];
            const float* wp = W2 + (size_t)oc*128 + ci;
#pragma unroll
            for (int j = 0; j < 16; ++j) acc[j] += f * wp[(size_t)j*128];
        }
#pragma unroll
        for (int j = 0; j < 16; ++j) {
            float v = fmaxf(acc[j] + B2[oc + j], 0.f);
            v = fmaxf(v, __shfl_xor(v, 1));
            v = fmaxf(v, __shfl_xor(v, 2));
            v = fmaxf(v, __shfl_xor(v, 4));
            v = fmaxf(v, __shfl_xor(v, 8));
            v = fmaxf(v, __shfl_xor(v, 16));
            v = fmaxf(v, __shfl_xor(v, 32));
            if (lane == 0) out[(size_t)gblk * 256 + oc + j] = v;
        }
    }
}

// ---------------------------------------------------------------------------
// SA3 layers as row-GEMM: out[row][oc] = relu(bias + in[row][:] . W[oc][:]).
// ---------------------------------------------------------------------------
template<int CIN, int COUT, bool CONCAT3>
__global__ __launch_bounds__(256)
void mlp_gemm_kernel(const float* __restrict__ inA, const float* __restrict__ inB,
                     const float* __restrict__ W, const float* __restrict__ Bb,
                     float* __restrict__ out)
{
    __shared__ float sft[128][65];
    const int tid = threadIdx.x, lane = tid & 63, wave = tid >> 6;
    const int row0 = blockIdx.x * 64;
    const int myoc0 = blockIdx.y * 64 + wave * 16;
    float acc[16];
#pragma unroll
    for (int j = 0; j < 16; ++j) acc[j] = 0.f;
    for (int c0 = 0; c0 < CIN; c0 += 128) {
        const int csz = (CIN - c0 < 128) ? (CIN - c0) : 128;
        for (int r = wave; r < 64; r += 4) {
            const int row = row0 + r;
            for (int cl = lane; cl < csz; cl += 64) {
                const int cig = c0 + cl;
                float v;
                if (CONCAT3)
                    v = (cig < 3) ? inA[(size_t)row*3 + cig]
                                  : inB[(size_t)row*(CIN-3) + (cig - 3)];
                else
                    v = inA[(size_t)row*CIN + cig];
                sft[cl][r] = v;
            }
        }
        __syncthreads();
        if (csz == 128) {
#pragma unroll 4
            for (int ci = 0; ci < 128; ++ci) {
                const float f = sft[ci][lane];
                const float* wp = W + (size_t)myoc0*CIN + c0 + ci;
#pragma unroll
                for (int j = 0; j < 16; ++j) acc[j] += f * wp[(size_t)j*CIN];
            }
        } else {
            for (int ci = 0; ci < csz; ++ci) {
                const float f = sft[ci][lane];
                const float* wp = W + (size_t)myoc0*CIN + c0 + ci;
#pragma unroll
                for (int j = 0; j < 16; ++j) acc[j] += f * wp[(size_t)j*CIN];
            }
        }
        __syncthreads();
    }
    const int row = row0 + lane;
#pragma unroll
    for (int j = 0; j < 16; ++j)
        out[(size_t)row*COUT + myoc0 + j] = fmaxf(acc[j] + Bb[myoc0 + j], 0.f);
}

// max over K=128 rows per batch: h3 [16*128][1024] -> g [16][1024]
__global__ __launch_bounds__(256)
void maxpool_kernel(const float* __restrict__ h3, float* __restrict__ g)
{
    const int i = blockIdx.x * 256 + threadIdx.x;   // 16*1024
    const int b = i >> 10, c = i & 1023;
    const float* p = h3 + (size_t)b * 128 * 1024 + c;
    float m = p[0];
    for (int k = 1; k < 128; ++k) m = fmaxf(m, p[(size_t)k * 1024]);
    g[i] = m;
}

// y[b][o] = fb[o] + g[b][:] . fw[o][:]; one wave per output
__global__ __launch_bounds__(256)
void fc_kernel(const float* __restrict__ g, const float* __restrict__ fw,
               const float* __restrict__ fb, float* __restrict__ y)
{
    const int gw = (blockIdx.x * 256 + threadIdx.x) >> 6;  // 0..16383
    const int lane = threadIdx.x & 63;
    const int b = gw >> 10, o = gw & 1023;
    const float4* gv = (const float4*)(g + (size_t)b * 1024);
    const float4* wv = (const float4*)(fw + (size_t)o * 1024);
    float acc = 0.f;
#pragma unroll
    for (int r = 0; r < 4; ++r) {
        const float4 gf = gv[lane + r*64];
        const float4 wf = wv[lane + r*64];
        acc += gf.x*wf.x + gf.y*wf.y + gf.z*wf.z + gf.w*wf.w;
    }
#pragma unroll
    for (int m = 32; m >= 1; m >>= 1) acc += __shfl_xor(acc, m);
    if (lane == 0) y[gw] = acc + fb[o];
}

extern "C" void kernel_launch(void* const* d_in, const int* in_sizes, int n_in,
                              void* d_out, int out_size, void* d_ws, size_t ws_size,
                              hipStream_t stream)
{
    (void)in_sizes; (void)n_in; (void)out_size; (void)ws_size;
    const float* x   = (const float*)d_in[0];
    const float* s1w0 = (const float*)d_in[1];  const float* s1b0 = (const float*)d_in[2];
    const float* s1w1 = (const float*)d_in[3];  const float* s1b1 = (const float*)d_in[4];
    const float* s1w2 = (const float*)d_in[5];  const float* s1b2 = (const float*)d_in[6];
    const float* s2w0 = (const float*)d_in[7];  const float* s2b0 = (const float*)d_in[8];
    const float* s2w1 = (const float*)d_in[9];  const float* s2b1 = (const float*)d_in[10];
    const float* s2w2 = (const float*)d_in[11]; const float* s2b2 = (const float*)d_in[12];
    const float* s3w0 = (const float*)d_in[13]; const float* s3b0 = (const float*)d_in[14];
    const float* s3w1 = (const float*)d_in[15]; const float* s3b1 = (const float*)d_in[16];
    const float* s3w2 = (const float*)d_in[17]; const float* s3b2 = (const float*)d_in[18];
    const float* fw  = (const float*)d_in[19]; const float* fb  = (const float*)d_in[20];
    float* y = (float*)d_out;

    char* ws = (char*)d_ws;
    float* l1_xyz = (float*)(ws + 0);          // 16*512*3
    int*   idx1   = (int*)  (ws + 98304);      // 16*512*32
    float* l1_pts = (float*)(ws + 1146880);    // 16*512*128
    float* l2_xyz = (float*)(ws + 5341184);    // 16*128*3
    int*   idx2   = (int*)  (ws + 5365760);    // 16*128*64
    float* l2_pts = (float*)(ws + 5890048);    // 16*128*256
    float* h1     = (float*)(ws + 7987200);    // 2048*256
    float* h2     = (float*)(ws + 10084352);   // 2048*512
    float* h3     = (float*)(ws + 14278656);   // 2048*1024
    float* g      = (float*)(ws + 22667264);   // 16*1024

    const float r2_1 = (float)(0.2 * 0.2);     // match JAX weak-type f64->f32 cast
    const float r2_2 = (float)(0.4 * 0.4);

    fps_kernel<4096, 512, 512><<<BATCH, 512, 0, stream>>>(x, l1_xyz);
    ballq_kernel<4096, 512, 32><<<(BATCH*512)/4, 256, 0, stream>>>(x, l1_xyz, idx1, r2_1);
    sa1_fused<<<(BATCH*512*32)/64, 256, 0, stream>>>(x, l1_xyz, idx1,
        s1w0, s1b0, s1w1, s1b1, s1w2, s1b2, l1_pts);
    fps_kernel<512, 128, 256><<<BATCH, 256, 0, stream>>>(l1_xyz, l2_xyz);
    ballq_kernel<512, 128, 64><<<(BATCH*128)/4, 256, 0, stream>>>(l1_xyz, l2_xyz, idx2, r2_2);
    sa2_fused<<<BATCH*128, 512, 0, stream>>>(l1_xyz, l1_pts, l2_xyz, idx2,
        s2w0, s2b0, s2w1, s2b1, s2w2, s2b2, l2_pts);
    mlp_gemm_kernel<259, 256, true ><<<dim3(32, 4),  256, 0, stream>>>(l2_xyz, l2_pts, s3w0, s3b0, h1);
    mlp_gemm_kernel<256, 512, false><<<dim3(32, 8),  256, 0, stream>>>(h1, nullptr, s3w1, s3b1, h2);
    mlp_gemm_kernel<512, 1024,false><<<dim3(32, 16), 256, 0, stream>>>(h2, nullptr, s3w2, s3b2, h3);
    maxpool_kernel<<<(BATCH*1024)/256, 256, 0, stream>>>(h3, g);
    fc_kernel<<<(BATCH*1024)/4, 256, 0, stream>>>(g, fw, fb, y);
}

// Round 3
// 1593.893 us; speedup vs baseline: 2.0080x; 1.5541x over previous
//
#include <hip/hip_runtime.h>

#ifndef BATCH
#define BATCH 16
#endif

// ---------------------------------------------------------------------------
// FPS: one block per batch. (unchanged, known-correct)
// ---------------------------------------------------------------------------
template<int N, int NPOINT, int BLOCK>
__global__ __launch_bounds__(BLOCK)
void fps_kernel(const float* __restrict__ xyz, float* __restrict__ out_xyz)
{
#pragma clang fp contract(off)
    constexpr int P = N / BLOCK;
    constexpr int NW = BLOCK / 64;
    __shared__ float sx[N], sy[N], sz[N];
    __shared__ float rv[NW];
    __shared__ int   ri[NW];
    const int b = blockIdx.x, t = threadIdx.x;
    const float* xb = xyz + (size_t)b * N * 3;
    float px[P], py[P], pz[P], dist[P];
#pragma unroll
    for (int j = 0; j < P; ++j) {
        const int i = t + j * BLOCK;
        const float x = xb[i*3+0], y = xb[i*3+1], z = xb[i*3+2];
        sx[i] = x; sy[i] = y; sz[i] = z;
        px[j] = x; py[j] = y; pz[j] = z;
        dist[j] = 1e10f;
    }
    __syncthreads();
    int far = 0;
    if (t == 0) {
        out_xyz[(size_t)b*NPOINT*3 + 0] = sx[0];
        out_xyz[(size_t)b*NPOINT*3 + 1] = sy[0];
        out_xyz[(size_t)b*NPOINT*3 + 2] = sz[0];
    }
    for (int s = 1; s < NPOINT; ++s) {
        const float fx = sx[far], fy = sy[far], fz = sz[far];
        float bestv = -1.f; int besti = 0x7fffffff;
#pragma unroll
        for (int j = 0; j < P; ++j) {
            const float dx = px[j]-fx, dy = py[j]-fy, dz = pz[j]-fz;
            const float d = (dx*dx + dy*dy) + dz*dz;
            const float nd = fminf(dist[j], d);
            dist[j] = nd;
            const int i = t + j * BLOCK;
            if (nd > bestv) { bestv = nd; besti = i; }
        }
#pragma unroll
        for (int m = 32; m >= 1; m >>= 1) {
            const float ov = __shfl_xor(bestv, m);
            const int   oi = __shfl_xor(besti, m);
            if (ov > bestv || (ov == bestv && oi < besti)) { bestv = ov; besti = oi; }
        }
        if ((t & 63) == 0) { rv[t >> 6] = bestv; ri[t >> 6] = besti; }
        __syncthreads();
        bestv = rv[0]; besti = ri[0];
#pragma unroll
        for (int w = 1; w < NW; ++w) {
            const float ov = rv[w]; const int oi = ri[w];
            if (ov > bestv || (ov == bestv && oi < besti)) { bestv = ov; besti = oi; }
        }
        far = besti;
        if (t == 0) {
            out_xyz[((size_t)b*NPOINT + s)*3 + 0] = sx[far];
            out_xyz[((size_t)b*NPOINT + s)*3 + 1] = sy[far];
            out_xyz[((size_t)b*NPOINT + s)*3 + 2] = sz[far];
        }
        __syncthreads();
    }
}

// ---------------------------------------------------------------------------
// Ball query (unchanged, known-correct)
// ---------------------------------------------------------------------------
template<int N, int S, int K>
__global__ __launch_bounds__(256)
void ballq_kernel(const float* __restrict__ xyz, const float* __restrict__ nxyz,
                  int* __restrict__ idx, const float r2)
{
#pragma clang fp contract(off)
    const int gw = (blockIdx.x * 256 + threadIdx.x) >> 6;
    const int lane = threadIdx.x & 63;
    const int b = gw / S, s = gw % S;
    const float* xb = xyz + (size_t)b * N * 3;
    const float qx = nxyz[((size_t)b*S + s)*3 + 0];
    const float qy = nxyz[((size_t)b*S + s)*3 + 1];
    const float qz = nxyz[((size_t)b*S + s)*3 + 2];
    int* op = idx + ((size_t)b*S + s) * K;
    int base = 0, first = -1;
    for (int c = 0; c < N; c += 64) {
        const int i = c + lane;
        const float dx = xb[i*3+0]-qx, dy = xb[i*3+1]-qy, dz = xb[i*3+2]-qz;
        const float d = (dx*dx + dy*dy) + dz*dz;
        const bool hit = !(d > r2);
        const unsigned long long m = __ballot(hit);
        if (first < 0 && m) first = c + __builtin_ctzll(m);
        const int pos = base + __popcll(m & ((1ull << lane) - 1ull));
        if (hit && pos < K) op[pos] = i;
        base += __popcll(m);
        if (base >= K) break;
    }
    if (base < K && lane >= base && lane < K) op[lane] = first;
}

// ---------------------------------------------------------------------------
// Weight transpose: W[O][C] -> Wt[C][O]  (tiny one-time prep)
// ---------------------------------------------------------------------------
template<int O, int C>
__global__ __launch_bounds__(256)
void transpose_kernel(const float* __restrict__ src, float* __restrict__ dst)
{
    const int i = blockIdx.x * 256 + threadIdx.x;
    if (i < O * C) {
        const int o = i / C, c = i % C;
        dst[c * O + o] = src[i];
    }
}

// 16 FMAs against 16 contiguous transposed weights (4x float4, 16B-aligned)
__device__ __forceinline__ void fma16(float (&acc)[16], const float f,
                                      const float* __restrict__ wrow)
{
    const float4 w0 = ((const float4*)wrow)[0];
    const float4 w1 = ((const float4*)wrow)[1];
    const float4 w2 = ((const float4*)wrow)[2];
    const float4 w3 = ((const float4*)wrow)[3];
    acc[0]+=f*w0.x;  acc[1]+=f*w0.y;  acc[2]+=f*w0.z;  acc[3]+=f*w0.w;
    acc[4]+=f*w1.x;  acc[5]+=f*w1.y;  acc[6]+=f*w1.z;  acc[7]+=f*w1.w;
    acc[8]+=f*w2.x;  acc[9]+=f*w2.y;  acc[10]+=f*w2.z; acc[11]+=f*w2.w;
    acc[12]+=f*w3.x; acc[13]+=f*w3.y; acc[14]+=f*w3.z; acc[15]+=f*w3.w;
}

// ---------------------------------------------------------------------------
// SA1 fused: block = 256 thr owns 64 rows (2 groups of K=32). lane=row,
// wave owns 16 ocs, activations ci-major in LDS, transposed weights.
// ---------------------------------------------------------------------------
__global__ __launch_bounds__(256)
void sa1_fused(const float* __restrict__ xyz, const float* __restrict__ nxyz,
               const int* __restrict__ idx,
               const float* __restrict__ Wt0, const float* __restrict__ B0,
               const float* __restrict__ Wt1, const float* __restrict__ B1,
               const float* __restrict__ Wt2, const float* __restrict__ B2,
               float* __restrict__ out)
{
    __shared__ float h1S[64][64];
    __shared__ float h2S[64][64];
    const int tid = threadIdx.x, lane = tid & 63;
    const int wave = __builtin_amdgcn_readfirstlane(tid >> 6);
    const int row0 = blockIdx.x * 64;
    const int myrow = row0 + lane;
    const int g = myrow >> 5, b = g >> 9;
    const int i = idx[myrow];
    const float* p = xyz + ((size_t)b*4096 + i) * 3;
    const float f0 = p[0] - nxyz[(size_t)g*3 + 0];
    const float f1 = p[1] - nxyz[(size_t)g*3 + 1];
    const float f2 = p[2] - nxyz[(size_t)g*3 + 2];
    const int oc0 = wave * 16;
    float acc[16];
    // L1: 3 -> 64
#pragma unroll
    for (int j = 0; j < 16; ++j)
        acc[j] = B0[oc0+j] + f0*Wt0[0*64+oc0+j] + f1*Wt0[1*64+oc0+j] + f2*Wt0[2*64+oc0+j];
#pragma unroll
    for (int j = 0; j < 16; ++j) h1S[oc0+j][lane] = fmaxf(acc[j], 0.f);
    __syncthreads();
    // L2: 64 -> 64
#pragma unroll
    for (int j = 0; j < 16; ++j) acc[j] = B1[oc0+j];
#pragma unroll 4
    for (int ci = 0; ci < 64; ++ci)
        fma16(acc, h1S[ci][lane], Wt1 + ci*64 + oc0);
#pragma unroll
    for (int j = 0; j < 16; ++j) h2S[oc0+j][lane] = fmaxf(acc[j], 0.f);
    __syncthreads();
    // L3: 64 -> 128 (2 passes) + maxpool over K=32 (half-wave)
    for (int pass = 0; pass < 2; ++pass) {
        const int oc = pass*64 + oc0;
#pragma unroll
        for (int j = 0; j < 16; ++j) acc[j] = B2[oc+j];
#pragma unroll 4
        for (int ci = 0; ci < 64; ++ci)
            fma16(acc, h2S[ci][lane], Wt2 + ci*128 + oc);
#pragma unroll
        for (int j = 0; j < 16; ++j) {
            float v = fmaxf(acc[j], 0.f);
            v = fmaxf(v, __shfl_xor(v, 1));
            v = fmaxf(v, __shfl_xor(v, 2));
            v = fmaxf(v, __shfl_xor(v, 4));
            v = fmaxf(v, __shfl_xor(v, 8));
            v = fmaxf(v, __shfl_xor(v, 16));
            if ((lane & 31) == 0)
                out[(size_t)((row0 + lane) >> 5) * 128 + oc + j] = v;
        }
    }
}

// ---------------------------------------------------------------------------
// SA2 fused: block = 256 thr owns 1 group (64 rows). lane=row, wave=16 ocs.
// Gathered feats ci-major [128][64] XOR-swizzled; h1 [128][64]; h2 reuses
// the gather buffer. LDS = 64 KB.
// ---------------------------------------------------------------------------
__global__ __launch_bounds__(256)
void sa2_fused(const float* __restrict__ l1xyz, const float* __restrict__ l1pts,
               const float* __restrict__ nxyz, const int* __restrict__ idx,
               const float* __restrict__ Wt0, const float* __restrict__ B0,
               const float* __restrict__ Wt1, const float* __restrict__ B1,
               const float* __restrict__ Wt2, const float* __restrict__ B2,
               float* __restrict__ out)
{
    __shared__ float featS[128][64];   // gather (swizzled), later h2 (plain)
    __shared__ float hS[128][64];      // h1
    const int tid = threadIdx.x, lane = tid & 63;
    const int wave = __builtin_amdgcn_readfirstlane(tid >> 6);
    const int gblk = blockIdx.x;                 // group 0..B*128-1
    const int b = gblk >> 7;
    const int row0 = gblk * 64;
    const int myi = idx[row0 + lane];
    const float* pc = l1xyz + ((size_t)b*512 + myi) * 3;
    const float f0 = pc[0] - nxyz[(size_t)gblk*3 + 0];
    const float f1 = pc[1] - nxyz[(size_t)gblk*3 + 1];
    const float f2 = pc[2] - nxyz[(size_t)gblk*3 + 2];
    // gather 128 feat channels x 64 rows; write [ci][r ^ (ci&63)] (conflict-free)
    for (int r = wave; r < 64; r += 4) {
        const int i2 = idx[row0 + r];
        const float* src = l1pts + ((size_t)b*512 + i2) * 128;
        featS[lane][r ^ lane]      = src[lane];
        featS[lane+64][r ^ lane]   = src[lane + 64];
    }
    __syncthreads();
    const int oc0 = wave * 16;
    float acc[16];
    // L1: 131 -> 128 (2 passes of 64 ocs)
    for (int pass = 0; pass < 2; ++pass) {
        const int oc = pass*64 + oc0;
#pragma unroll
        for (int j = 0; j < 16; ++j)
            acc[j] = B0[oc+j] + f0*Wt0[0*128+oc+j] + f1*Wt0[1*128+oc+j] + f2*Wt0[2*128+oc+j];
#pragma unroll 4
        for (int ci = 0; ci < 128; ++ci)
            fma16(acc, featS[ci][lane ^ (ci & 63)], Wt0 + (size_t)(ci+3)*128 + oc);
#pragma unroll
        for (int j = 0; j < 16; ++j) hS[oc+j][lane] = fmaxf(acc[j], 0.f);
    }
    __syncthreads();   // featS reads done; hS complete
    // L2: 128 -> 128, write h2 into featS (plain [ch][row])
    for (int pass = 0; pass < 2; ++pass) {
        const int oc = pass*64 + oc0;
#pragma unroll
        for (int j = 0; j < 16; ++j) acc[j] = B1[oc+j];
#pragma unroll 4
        for (int ci = 0; ci < 128; ++ci)
            fma16(acc, hS[ci][lane], Wt1 + (size_t)ci*128 + oc);
#pragma unroll
        for (int j = 0; j < 16; ++j) featS[oc+j][lane] = fmaxf(acc[j], 0.f);
    }
    __syncthreads();
    // L3: 128 -> 256 (4 passes) + maxpool over K=64
    float* orow = out + (size_t)gblk * 256;
    for (int pass = 0; pass < 4; ++pass) {
        const int oc = pass*64 + oc0;
#pragma unroll
        for (int j = 0; j < 16; ++j) acc[j] = B2[oc+j];
#pragma unroll 4
        for (int ci = 0; ci < 128; ++ci)
            fma16(acc, featS[ci][lane], Wt2 + (size_t)ci*256 + oc);
#pragma unroll
        for (int j = 0; j < 16; ++j) {
            float v = fmaxf(acc[j], 0.f);
            v = fmaxf(v, __shfl_xor(v, 1));
            v = fmaxf(v, __shfl_xor(v, 2));
            v = fmaxf(v, __shfl_xor(v, 4));
            v = fmaxf(v, __shfl_xor(v, 8));
            v = fmaxf(v, __shfl_xor(v, 16));
            v = fmaxf(v, __shfl_xor(v, 32));
            if (lane == 0) orow[oc + j] = v;
        }
    }
}

// ---------------------------------------------------------------------------
// SA3 GEMM layers: block = 64 rows x 64 ocs, ci staged 128 at a time in LDS.
// POOL=true fuses per-64-row maxpool (writes partial-max rows).
// ---------------------------------------------------------------------------
template<int CIN, int COUT, bool CONCAT3, bool POOL>
__global__ __launch_bounds__(256)
void mlp_gemm_kernel(const float* __restrict__ inA, const float* __restrict__ inB,
                     const float* __restrict__ Wt, const float* __restrict__ Bb,
                     float* __restrict__ out)
{
    __shared__ float featS[128][64];
    const int tid = threadIdx.x, lane = tid & 63;
    const int wave = __builtin_amdgcn_readfirstlane(tid >> 6);
    const int row0 = blockIdx.x * 64;
    const int oc0 = blockIdx.y * 64 + wave * 16;
    float acc[16];
#pragma unroll
    for (int j = 0; j < 16; ++j) acc[j] = Bb[oc0 + j];
    for (int c0 = 0; c0 < CIN; c0 += 128) {
        const int csz = (CIN - c0 < 128) ? (CIN - c0) : 128;
        __syncthreads();
        for (int r = wave; r < 64; r += 4) {
            const int row = row0 + r;
            for (int cl = lane; cl < csz; cl += 64) {
                const int cig = c0 + cl;
                float v;
                if (CONCAT3)
                    v = (cig < 3) ? inA[(size_t)row*3 + cig]
                                  : inB[(size_t)row*(CIN-3) + (cig - 3)];
                else
                    v = inA[(size_t)row*CIN + cig];
                featS[cl][r ^ (cl & 63)] = v;
            }
        }
        __syncthreads();
        if (csz == 128) {
#pragma unroll 4
            for (int ci = 0; ci < 128; ++ci)
                fma16(acc, featS[ci][lane ^ (ci & 63)], Wt + (size_t)(c0+ci)*COUT + oc0);
        } else {
            for (int ci = 0; ci < csz; ++ci)
                fma16(acc, featS[ci][lane ^ (ci & 63)], Wt + (size_t)(c0+ci)*COUT + oc0);
        }
    }
    if (POOL) {
#pragma unroll
        for (int j = 0; j < 16; ++j) {
            float v = fmaxf(acc[j], 0.f);
            v = fmaxf(v, __shfl_xor(v, 1));
            v = fmaxf(v, __shfl_xor(v, 2));
            v = fmaxf(v, __shfl_xor(v, 4));
            v = fmaxf(v, __shfl_xor(v, 8));
            v = fmaxf(v, __shfl_xor(v, 16));
            v = fmaxf(v, __shfl_xor(v, 32));
            if (lane == 0) out[(size_t)blockIdx.x * COUT + oc0 + j] = v;
        }
    } else {
        float4 o0, o1, o2, o3;
        o0.x=fmaxf(acc[0],0.f);  o0.y=fmaxf(acc[1],0.f);  o0.z=fmaxf(acc[2],0.f);  o0.w=fmaxf(acc[3],0.f);
        o1.x=fmaxf(acc[4],0.f);  o1.y=fmaxf(acc[5],0.f);  o1.z=fmaxf(acc[6],0.f);  o1.w=fmaxf(acc[7],0.f);
        o2.x=fmaxf(acc[8],0.f);  o2.y=fmaxf(acc[9],0.f);  o2.z=fmaxf(acc[10],0.f); o2.w=fmaxf(acc[11],0.f);
        o3.x=fmaxf(acc[12],0.f); o3.y=fmaxf(acc[13],0.f); o3.z=fmaxf(acc[14],0.f); o3.w=fmaxf(acc[15],0.f);
        float4* op = (float4*)(out + (size_t)(row0 + lane)*COUT + oc0);
        op[0]=o0; op[1]=o1; op[2]=o2; op[3]=o3;
    }
}

// y[b][o] = fb[o] + max(pmax[2b], pmax[2b+1]) . fw[o]; one wave per output
__global__ __launch_bounds__(256)
void fc_kernel(const float* __restrict__ pmax, const float* __restrict__ fw,
               const float* __restrict__ fb, float* __restrict__ y)
{
    const int gw = (blockIdx.x * 256 + threadIdx.x) >> 6;
    const int lane = threadIdx.x & 63;
    const int b = gw >> 10, o = gw & 1023;
    const float4* g0 = (const float4*)(pmax + (size_t)(2*b) * 1024);
    const float4* g1 = (const float4*)(pmax + (size_t)(2*b+1) * 1024);
    const float4* wv = (const float4*)(fw + (size_t)o * 1024);
    float acc = 0.f;
#pragma unroll
    for (int r = 0; r < 4; ++r) {
        const float4 a = g0[lane + r*64];
        const float4 c = g1[lane + r*64];
        const float4 w = wv[lane + r*64];
        acc += fmaxf(a.x,c.x)*w.x + fmaxf(a.y,c.y)*w.y
             + fmaxf(a.z,c.z)*w.z + fmaxf(a.w,c.w)*w.w;
    }
#pragma unroll
    for (int m = 32; m >= 1; m >>= 1) acc += __shfl_xor(acc, m);
    if (lane == 0) y[gw] = acc + fb[o];
}

extern "C" void kernel_launch(void* const* d_in, const int* in_sizes, int n_in,
                              void* d_out, int out_size, void* d_ws, size_t ws_size,
                              hipStream_t stream)
{
    (void)in_sizes; (void)n_in; (void)out_size; (void)ws_size;
    const float* x   = (const float*)d_in[0];
    const float* s1w0 = (const float*)d_in[1];  const float* s1b0 = (const float*)d_in[2];
    const float* s1w1 = (const float*)d_in[3];  const float* s1b1 = (const float*)d_in[4];
    const float* s1w2 = (const float*)d_in[5];  const float* s1b2 = (const float*)d_in[6];
    const float* s2w0 = (const float*)d_in[7];  const float* s2b0 = (const float*)d_in[8];
    const float* s2w1 = (const float*)d_in[9];  const float* s2b1 = (const float*)d_in[10];
    const float* s2w2 = (const float*)d_in[11]; const float* s2b2 = (const float*)d_in[12];
    const float* s3w0 = (const float*)d_in[13]; const float* s3b0 = (const float*)d_in[14];
    const float* s3w1 = (const float*)d_in[15]; const float* s3b1 = (const float*)d_in[16];
    const float* s3w2 = (const float*)d_in[17]; const float* s3b2 = (const float*)d_in[18];
    const float* fw  = (const float*)d_in[19]; const float* fb  = (const float*)d_in[20];
    float* y = (float*)d_out;

    char* ws = (char*)d_ws;
    float* l1_xyz = (float*)(ws + 0);          // 16*512*3
    int*   idx1   = (int*)  (ws + 98304);      // 16*512*32
    float* l1_pts = (float*)(ws + 1146880);    // 16*512*128
    float* l2_xyz = (float*)(ws + 5341184);    // 16*128*3
    int*   idx2   = (int*)  (ws + 5365760);    // 16*128*64
    float* l2_pts = (float*)(ws + 5890048);    // 16*128*256
    float* h1     = (float*)(ws + 7987200);    // 2048*256
    float* h2     = (float*)(ws + 10084352);   // 2048*512
    float* pmax   = (float*)(ws + 14278656);   // 32*1024 partial maxes
    float* wt1_0  = (float*)(ws + 14409728);   // [3][64]
    float* wt1_1  = (float*)(ws + 14410496);   // [64][64]
    float* wt1_2  = (float*)(ws + 14426880);   // [64][128]
    float* wt2_0  = (float*)(ws + 14459648);   // [131][128]
    float* wt2_1  = (float*)(ws + 14526720);   // [128][128]
    float* wt2_2  = (float*)(ws + 14592256);   // [128][256]
    float* wt3_0  = (float*)(ws + 14723328);   // [259][256]
    float* wt3_1  = (float*)(ws + 14988544);   // [256][512]
    float* wt3_2  = (float*)(ws + 15512832);   // [512][1024]

    const float r2_1 = (float)(0.2 * 0.2);
    const float r2_2 = (float)(0.4 * 0.4);

    // one-time weight transposes (graph-captured each launch; tiny)
    transpose_kernel<64,3>    <<<1,    256, 0, stream>>>(s1w0, wt1_0);
    transpose_kernel<64,64>   <<<16,   256, 0, stream>>>(s1w1, wt1_1);
    transpose_kernel<128,64>  <<<32,   256, 0, stream>>>(s1w2, wt1_2);
    transpose_kernel<128,131> <<<66,   256, 0, stream>>>(s2w0, wt2_0);
    transpose_kernel<128,128> <<<64,   256, 0, stream>>>(s2w1, wt2_1);
    transpose_kernel<256,128> <<<128,  256, 0, stream>>>(s2w2, wt2_2);
    transpose_kernel<256,259> <<<260,  256, 0, stream>>>(s3w0, wt3_0);
    transpose_kernel<512,256> <<<512,  256, 0, stream>>>(s3w1, wt3_1);
    transpose_kernel<1024,512><<<2048, 256, 0, stream>>>(s3w2, wt3_2);

    fps_kernel<4096, 512, 512><<<BATCH, 512, 0, stream>>>(x, l1_xyz);
    ballq_kernel<4096, 512, 32><<<(BATCH*512)/4, 256, 0, stream>>>(x, l1_xyz, idx1, r2_1);
    sa1_fused<<<(BATCH*512*32)/64, 256, 0, stream>>>(x, l1_xyz, idx1,
        wt1_0, s1b0, wt1_1, s1b1, wt1_2, s1b2, l1_pts);
    fps_kernel<512, 128, 256><<<BATCH, 256, 0, stream>>>(l1_xyz, l2_xyz);
    ballq_kernel<512, 128, 64><<<(BATCH*128)/4, 256, 0, stream>>>(l1_xyz, l2_xyz, idx2, r2_2);
    sa2_fused<<<BATCH*128, 256, 0, stream>>>(l1_xyz, l1_pts, l2_xyz, idx2,
        wt2_0, s2b0, wt2_1, s2b1, wt2_2, s2b2, l2_pts);
    mlp_gemm_kernel<259, 256,  true,  false><<<dim3(32, 4),  256, 0, stream>>>(l2_xyz, l2_pts, wt3_0, s3b0, h1);
    mlp_gemm_kernel<256, 512,  false, false><<<dim3(32, 8),  256, 0, stream>>>(h1, nullptr, wt3_1, s3b1, h2);
    mlp_gemm_kernel<512, 1024, false, true ><<<dim3(32, 16), 256, 0, stream>>>(h2, nullptr, wt3_2, s3b2, pmax);
    fc_kernel<<<(BATCH*1024)/4, 256, 0, stream>>>(pmax, fw, fb, y);
}

// Round 4
// 1211.217 us; speedup vs baseline: 2.6424x; 1.3159x over previous
//
#include <hip/hip_runtime.h>

#ifndef BATCH
#define BATCH 16
#endif

// ---------------------------------------------------------------------------
// Fused FPS (both stages). One block per batch.
// Stage 1: FPS over N=4096 points -> NP1=512 (coords to out1 + LDS).
// Stage 2: FPS over those 512     -> NP2=128 (coords to out2).
// Per step: one barrier. Block argmax via packed u64 (dist_bits<<32 | ~idx)
// wave-shuffle max + one LDS atomicMax per wave into a 3-slot rotation.
// Bit-exact distances: contract(off), (dx*dx+dy*dy)+dz*dz, strict-> select.
// ---------------------------------------------------------------------------
template<int N, int NP1, int NP2, int BLOCK>
__global__ __launch_bounds__(BLOCK)
void fps_fused(const float* __restrict__ xyz,
               float* __restrict__ out1, float* __restrict__ out2)
{
#pragma clang fp contract(off)
    constexpr int P = N / BLOCK;
    __shared__ float sx[N], sy[N], sz[N];
    __shared__ float s2x[NP1], s2y[NP1], s2z[NP1];
    __shared__ unsigned long long slot[3];
    const int b = blockIdx.x, t = threadIdx.x;
    const float* xb = xyz + (size_t)b * N * 3;
    float px[P], py[P], pz[P], dist[P];
#pragma unroll
    for (int j = 0; j < P; ++j) {
        const int i = t + j * BLOCK;
        const float x = xb[i*3+0], y = xb[i*3+1], z = xb[i*3+2];
        sx[i] = x; sy[i] = y; sz[i] = z;
        px[j] = x; py[j] = y; pz[j] = z;
        dist[j] = 1e10f;
    }
    if (t < 3) slot[t] = 0ull;
    __syncthreads();
    int far = 0;
    if (t == 0) {
        out1[(size_t)b*NP1*3 + 0] = sx[0];
        out1[(size_t)b*NP1*3 + 1] = sy[0];
        out1[(size_t)b*NP1*3 + 2] = sz[0];
        s2x[0] = sx[0]; s2y[0] = sy[0]; s2z[0] = sz[0];
    }
    for (int s = 1; s < NP1; ++s) {
        const float fx = sx[far], fy = sy[far], fz = sz[far];
        float bestv = -1.f; int besti = 0;
#pragma unroll
        for (int j = 0; j < P; ++j) {
            const float dx = px[j]-fx, dy = py[j]-fy, dz = pz[j]-fz;
            const float d = (dx*dx + dy*dy) + dz*dz;
            const float nd = fminf(dist[j], d);
            dist[j] = nd;
            if (nd > bestv) { bestv = nd; besti = t + j * BLOCK; }
        }
        unsigned long long pk =
            ((unsigned long long)__float_as_uint(bestv) << 32) | (unsigned)(~besti);
#pragma unroll
        for (int m = 32; m >= 1; m >>= 1) {
            const unsigned long long o = __shfl_xor(pk, m);
            pk = (o > pk) ? o : pk;
        }
        if ((t & 63) == 0) atomicMax(&slot[s % 3], pk);
        if (t == 0) slot[(s + 1) % 3] = 0ull;   // safe: last read 2 steps ago
        __syncthreads();
        pk = slot[s % 3];
        far = (int)(~(unsigned)pk);
        if (t == 0) {
            const float X = sx[far], Y = sy[far], Z = sz[far];
            out1[((size_t)b*NP1 + s)*3 + 0] = X;
            out1[((size_t)b*NP1 + s)*3 + 1] = Y;
            out1[((size_t)b*NP1 + s)*3 + 2] = Z;
            s2x[s] = X; s2y[s] = Y; s2z[s] = Z;
        }
    }
    __syncthreads();             // s2 arrays complete
    if (t < 3) slot[t] = 0ull;   // clear rotation for stage 2
    __syncthreads();
    // -------- stage 2: FPS over NP1 sampled points (1 point per thread) -----
    const bool own = (t < NP1);
    const float mx = own ? s2x[t] : 0.f;
    const float my = own ? s2y[t] : 0.f;
    const float mz = own ? s2z[t] : 0.f;
    float d2 = 1e10f;
    int far2 = 0;
    if (t == 0) {
        out2[(size_t)b*NP2*3 + 0] = s2x[0];
        out2[(size_t)b*NP2*3 + 1] = s2y[0];
        out2[(size_t)b*NP2*3 + 2] = s2z[0];
    }
    for (int s = 1; s < NP2; ++s) {
        const float fx = s2x[far2], fy = s2y[far2], fz = s2z[far2];
        float bestv = -1.f; int besti = 0;
        if (own) {
            const float dx = mx-fx, dy = my-fy, dz = mz-fz;
            const float d = (dx*dx + dy*dy) + dz*dz;
            d2 = fminf(d2, d);
            bestv = d2; besti = t;
        }
        unsigned long long pk =
            ((unsigned long long)__float_as_uint(bestv) << 32) | (unsigned)(~besti);
#pragma unroll
        for (int m = 32; m >= 1; m >>= 1) {
            const unsigned long long o = __shfl_xor(pk, m);
            pk = (o > pk) ? o : pk;
        }
        if ((t & 63) == 0) atomicMax(&slot[s % 3], pk);
        if (t == 0) slot[(s + 1) % 3] = 0ull;
        __syncthreads();
        pk = slot[s % 3];
        far2 = (int)(~(unsigned)pk);
        if (t == 0) {
            out2[((size_t)b*NP2 + s)*3 + 0] = s2x[far2];
            out2[((size_t)b*NP2 + s)*3 + 1] = s2y[far2];
            out2[((size_t)b*NP2 + s)*3 + 2] = s2z[far2];
        }
    }
}

// ---------------------------------------------------------------------------
// Ball query (unchanged, known-correct)
// ---------------------------------------------------------------------------
template<int N, int S, int K>
__global__ __launch_bounds__(256)
void ballq_kernel(const float* __restrict__ xyz, const float* __restrict__ nxyz,
                  int* __restrict__ idx, const float r2)
{
#pragma clang fp contract(off)
    const int gw = (blockIdx.x * 256 + threadIdx.x) >> 6;
    const int lane = threadIdx.x & 63;
    const int b = gw / S, s = gw % S;
    const float* xb = xyz + (size_t)b * N * 3;
    const float qx = nxyz[((size_t)b*S + s)*3 + 0];
    const float qy = nxyz[((size_t)b*S + s)*3 + 1];
    const float qz = nxyz[((size_t)b*S + s)*3 + 2];
    int* op = idx + ((size_t)b*S + s) * K;
    int base = 0, first = -1;
    for (int c = 0; c < N; c += 64) {
        const int i = c + lane;
        const float dx = xb[i*3+0]-qx, dy = xb[i*3+1]-qy, dz = xb[i*3+2]-qz;
        const float d = (dx*dx + dy*dy) + dz*dz;
        const bool hit = !(d > r2);
        const unsigned long long m = __ballot(hit);
        if (first < 0 && m) first = c + __builtin_ctzll(m);
        const int pos = base + __popcll(m & ((1ull << lane) - 1ull));
        if (hit && pos < K) op[pos] = i;
        base += __popcll(m);
        if (base >= K) break;
    }
    if (base < K && lane >= base && lane < K) op[lane] = first;
}

// ---------------------------------------------------------------------------
// All 9 weight transposes W[O][C] -> Wt[C][O] in one launch.
// ---------------------------------------------------------------------------
__global__ __launch_bounds__(256)
void transpose_all(const float* __restrict__ s0, float* __restrict__ d0,
                   const float* __restrict__ s1, float* __restrict__ d1,
                   const float* __restrict__ s2, float* __restrict__ d2,
                   const float* __restrict__ s3, float* __restrict__ d3,
                   const float* __restrict__ s4, float* __restrict__ d4,
                   const float* __restrict__ s5, float* __restrict__ d5,
                   const float* __restrict__ s6, float* __restrict__ d6,
                   const float* __restrict__ s7, float* __restrict__ d7,
                   const float* __restrict__ s8, float* __restrict__ d8)
{
    int i = blockIdx.x * 256 + threadIdx.x;
    if (i < 192)    { d0[(i%3)  *64   + i/3  ] = s0[i]; return; }  i -= 192;
    if (i < 4096)   { d1[(i&63) *64   + (i>>6)] = s1[i]; return; } i -= 4096;
    if (i < 8192)   { d2[(i&63) *128  + (i>>6)] = s2[i]; return; } i -= 8192;
    if (i < 16768)  { d3[(i%131)*128  + i/131] = s3[i]; return; }  i -= 16768;
    if (i < 16384)  { d4[(i&127)*128  + (i>>7)] = s4[i]; return; } i -= 16384;
    if (i < 32768)  { d5[(i&127)*256  + (i>>7)] = s5[i]; return; } i -= 32768;
    if (i < 66304)  { d6[(i%259)*256  + i/259] = s6[i]; return; }  i -= 66304;
    if (i < 131072) { d7[(i&255)*512  + (i>>8)] = s7[i]; return; } i -= 131072;
    if (i < 524288) { d8[(i&511)*1024 + (i>>9)] = s8[i]; return; }
}

// 16 FMAs against 16 contiguous transposed weights (4x float4, 16B-aligned)
__device__ __forceinline__ void fma16(float (&acc)[16], const float f,
                                      const float* __restrict__ wrow)
{
    const float4 w0 = ((const float4*)wrow)[0];
    const float4 w1 = ((const float4*)wrow)[1];
    const float4 w2 = ((const float4*)wrow)[2];
    const float4 w3 = ((const float4*)wrow)[3];
    acc[0]+=f*w0.x;  acc[1]+=f*w0.y;  acc[2]+=f*w0.z;  acc[3]+=f*w0.w;
    acc[4]+=f*w1.x;  acc[5]+=f*w1.y;  acc[6]+=f*w1.z;  acc[7]+=f*w1.w;
    acc[8]+=f*w2.x;  acc[9]+=f*w2.y;  acc[10]+=f*w2.z; acc[11]+=f*w2.w;
    acc[12]+=f*w3.x; acc[13]+=f*w3.y; acc[14]+=f*w3.z; acc[15]+=f*w3.w;
}

// ---------------------------------------------------------------------------
// SA1 fused (unchanged from R3)
// ---------------------------------------------------------------------------
__global__ __launch_bounds__(256)
void sa1_fused(const float* __restrict__ xyz, const float* __restrict__ nxyz,
               const int* __restrict__ idx,
               const float* __restrict__ Wt0, const float* __restrict__ B0,
               const float* __restrict__ Wt1, const float* __restrict__ B1,
               const float* __restrict__ Wt2, const float* __restrict__ B2,
               float* __restrict__ out)
{
    __shared__ float h1S[64][64];
    __shared__ float h2S[64][64];
    const int tid = threadIdx.x, lane = tid & 63;
    const int wave = __builtin_amdgcn_readfirstlane(tid >> 6);
    const int row0 = blockIdx.x * 64;
    const int myrow = row0 + lane;
    const int g = myrow >> 5, b = g >> 9;
    const int i = idx[myrow];
    const float* p = xyz + ((size_t)b*4096 + i) * 3;
    const float f0 = p[0] - nxyz[(size_t)g*3 + 0];
    const float f1 = p[1] - nxyz[(size_t)g*3 + 1];
    const float f2 = p[2] - nxyz[(size_t)g*3 + 2];
    const int oc0 = wave * 16;
    float acc[16];
#pragma unroll
    for (int j = 0; j < 16; ++j)
        acc[j] = B0[oc0+j] + f0*Wt0[0*64+oc0+j] + f1*Wt0[1*64+oc0+j] + f2*Wt0[2*64+oc0+j];
#pragma unroll
    for (int j = 0; j < 16; ++j) h1S[oc0+j][lane] = fmaxf(acc[j], 0.f);
    __syncthreads();
#pragma unroll
    for (int j = 0; j < 16; ++j) acc[j] = B1[oc0+j];
#pragma unroll 4
    for (int ci = 0; ci < 64; ++ci)
        fma16(acc, h1S[ci][lane], Wt1 + ci*64 + oc0);
#pragma unroll
    for (int j = 0; j < 16; ++j) h2S[oc0+j][lane] = fmaxf(acc[j], 0.f);
    __syncthreads();
    for (int pass = 0; pass < 2; ++pass) {
        const int oc = pass*64 + oc0;
#pragma unroll
        for (int j = 0; j < 16; ++j) acc[j] = B2[oc+j];
#pragma unroll 4
        for (int ci = 0; ci < 64; ++ci)
            fma16(acc, h2S[ci][lane], Wt2 + ci*128 + oc);
#pragma unroll
        for (int j = 0; j < 16; ++j) {
            float v = fmaxf(acc[j], 0.f);
            v = fmaxf(v, __shfl_xor(v, 1));
            v = fmaxf(v, __shfl_xor(v, 2));
            v = fmaxf(v, __shfl_xor(v, 4));
            v = fmaxf(v, __shfl_xor(v, 8));
            v = fmaxf(v, __shfl_xor(v, 16));
            if ((lane & 31) == 0)
                out[(size_t)((row0 + lane) >> 5) * 128 + oc + j] = v;
        }
    }
}

// ---------------------------------------------------------------------------
// SA2 fused (unchanged from R3)
// ---------------------------------------------------------------------------
__global__ __launch_bounds__(256)
void sa2_fused(const float* __restrict__ l1xyz, const float* __restrict__ l1pts,
               const float* __restrict__ nxyz, const int* __restrict__ idx,
               const float* __restrict__ Wt0, const float* __restrict__ B0,
               const float* __restrict__ Wt1, const float* __restrict__ B1,
               const float* __restrict__ Wt2, const float* __restrict__ B2,
               float* __restrict__ out)
{
    __shared__ float featS[128][64];
    __shared__ float hS[128][64];
    const int tid = threadIdx.x, lane = tid & 63;
    const int wave = __builtin_amdgcn_readfirstlane(tid >> 6);
    const int gblk = blockIdx.x;
    const int b = gblk >> 7;
    const int row0 = gblk * 64;
    const int myi = idx[row0 + lane];
    const float* pc = l1xyz + ((size_t)b*512 + myi) * 3;
    const float f0 = pc[0] - nxyz[(size_t)gblk*3 + 0];
    const float f1 = pc[1] - nxyz[(size_t)gblk*3 + 1];
    const float f2 = pc[2] - nxyz[(size_t)gblk*3 + 2];
    for (int r = wave; r < 64; r += 4) {
        const int i2 = idx[row0 + r];
        const float* src = l1pts + ((size_t)b*512 + i2) * 128;
        featS[lane][r ^ lane]    = src[lane];
        featS[lane+64][r ^ lane] = src[lane + 64];
    }
    __syncthreads();
    const int oc0 = wave * 16;
    float acc[16];
    for (int pass = 0; pass < 2; ++pass) {
        const int oc = pass*64 + oc0;
#pragma unroll
        for (int j = 0; j < 16; ++j)
            acc[j] = B0[oc+j] + f0*Wt0[0*128+oc+j] + f1*Wt0[1*128+oc+j] + f2*Wt0[2*128+oc+j];
#pragma unroll 4
        for (int ci = 0; ci < 128; ++ci)
            fma16(acc, featS[ci][lane ^ (ci & 63)], Wt0 + (size_t)(ci+3)*128 + oc);
#pragma unroll
        for (int j = 0; j < 16; ++j) hS[oc+j][lane] = fmaxf(acc[j], 0.f);
    }
    __syncthreads();
    for (int pass = 0; pass < 2; ++pass) {
        const int oc = pass*64 + oc0;
#pragma unroll
        for (int j = 0; j < 16; ++j) acc[j] = B1[oc+j];
#pragma unroll 4
        for (int ci = 0; ci < 128; ++ci)
            fma16(acc, hS[ci][lane], Wt1 + (size_t)ci*128 + oc);
#pragma unroll
        for (int j = 0; j < 16; ++j) featS[oc+j][lane] = fmaxf(acc[j], 0.f);
    }
    __syncthreads();
    float* orow = out + (size_t)gblk * 256;
    for (int pass = 0; pass < 4; ++pass) {
        const int oc = pass*64 + oc0;
#pragma unroll
        for (int j = 0; j < 16; ++j) acc[j] = B2[oc+j];
#pragma unroll 4
        for (int ci = 0; ci < 128; ++ci)
            fma16(acc, featS[ci][lane], Wt2 + (size_t)ci*256 + oc);
#pragma unroll
        for (int j = 0; j < 16; ++j) {
            float v = fmaxf(acc[j], 0.f);
            v = fmaxf(v, __shfl_xor(v, 1));
            v = fmaxf(v, __shfl_xor(v, 2));
            v = fmaxf(v, __shfl_xor(v, 4));
            v = fmaxf(v, __shfl_xor(v, 8));
            v = fmaxf(v, __shfl_xor(v, 16));
            v = fmaxf(v, __shfl_xor(v, 32));
            if (lane == 0) orow[oc + j] = v;
        }
    }
}

// ---------------------------------------------------------------------------
// SA3 GEMM layers (unchanged from R3)
// ---------------------------------------------------------------------------
template<int CIN, int COUT, bool CONCAT3, bool POOL>
__global__ __launch_bounds__(256)
void mlp_gemm_kernel(const float* __restrict__ inA, const float* __restrict__ inB,
                     const float* __restrict__ Wt, const float* __restrict__ Bb,
                     float* __restrict__ out)
{
    __shared__ float featS[128][64];
    const int tid = threadIdx.x, lane = tid & 63;
    const int wave = __builtin_amdgcn_readfirstlane(tid >> 6);
    const int row0 = blockIdx.x * 64;
    const int oc0 = blockIdx.y * 64 + wave * 16;
    float acc[16];
#pragma unroll
    for (int j = 0; j < 16; ++j) acc[j] = Bb[oc0 + j];
    for (int c0 = 0; c0 < CIN; c0 += 128) {
        const int csz = (CIN - c0 < 128) ? (CIN - c0) : 128;
        __syncthreads();
        for (int r = wave; r < 64; r += 4) {
            const int row = row0 + r;
            for (int cl = lane; cl < csz; cl += 64) {
                const int cig = c0 + cl;
                float v;
                if (CONCAT3)
                    v = (cig < 3) ? inA[(size_t)row*3 + cig]
                                  : inB[(size_t)row*(CIN-3) + (cig - 3)];
                else
                    v = inA[(size_t)row*CIN + cig];
                featS[cl][r ^ (cl & 63)] = v;
            }
        }
        __syncthreads();
        if (csz == 128) {
#pragma unroll 4
            for (int ci = 0; ci < 128; ++ci)
                fma16(acc, featS[ci][lane ^ (ci & 63)], Wt + (size_t)(c0+ci)*COUT + oc0);
        } else {
            for (int ci = 0; ci < csz; ++ci)
                fma16(acc, featS[ci][lane ^ (ci & 63)], Wt + (size_t)(c0+ci)*COUT + oc0);
        }
    }
    if (POOL) {
#pragma unroll
        for (int j = 0; j < 16; ++j) {
            float v = fmaxf(acc[j], 0.f);
            v = fmaxf(v, __shfl_xor(v, 1));
            v = fmaxf(v, __shfl_xor(v, 2));
            v = fmaxf(v, __shfl_xor(v, 4));
            v = fmaxf(v, __shfl_xor(v, 8));
            v = fmaxf(v, __shfl_xor(v, 16));
            v = fmaxf(v, __shfl_xor(v, 32));
            if (lane == 0) out[(size_t)blockIdx.x * COUT + oc0 + j] = v;
        }
    } else {
        float4 o0, o1, o2, o3;
        o0.x=fmaxf(acc[0],0.f);  o0.y=fmaxf(acc[1],0.f);  o0.z=fmaxf(acc[2],0.f);  o0.w=fmaxf(acc[3],0.f);
        o1.x=fmaxf(acc[4],0.f);  o1.y=fmaxf(acc[5],0.f);  o1.z=fmaxf(acc[6],0.f);  o1.w=fmaxf(acc[7],0.f);
        o2.x=fmaxf(acc[8],0.f);  o2.y=fmaxf(acc[9],0.f);  o2.z=fmaxf(acc[10],0.f); o2.w=fmaxf(acc[11],0.f);
        o3.x=fmaxf(acc[12],0.f); o3.y=fmaxf(acc[13],0.f); o3.z=fmaxf(acc[14],0.f); o3.w=fmaxf(acc[15],0.f);
        float4* op = (float4*)(out + (size_t)(row0 + lane)*COUT + oc0);
        op[0]=o0; op[1]=o1; op[2]=o2; op[3]=o3;
    }
}

// y[b][o] = fb[o] + max(pmax[2b], pmax[2b+1]) . fw[o]; one wave per output
__global__ __launch_bounds__(256)
void fc_kernel(const float* __restrict__ pmax, const float* __restrict__ fw,
               const float* __restrict__ fb, float* __restrict__ y)
{
    const int gw = (blockIdx.x * 256 + threadIdx.x) >> 6;
    const int lane = threadIdx.x & 63;
    const int b = gw >> 10, o = gw & 1023;
    const float4* g0 = (const float4*)(pmax + (size_t)(2*b) * 1024);
    const float4* g1 = (const float4*)(pmax + (size_t)(2*b+1) * 1024);
    const float4* wv = (const float4*)(fw + (size_t)o * 1024);
    float acc = 0.f;
#pragma unroll
    for (int r = 0; r < 4; ++r) {
        const float4 a = g0[lane + r*64];
        const float4 c = g1[lane + r*64];
        const float4 w = wv[lane + r*64];
        acc += fmaxf(a.x,c.x)*w.x + fmaxf(a.y,c.y)*w.y
             + fmaxf(a.z,c.z)*w.z + fmaxf(a.w,c.w)*w.w;
    }
#pragma unroll
    for (int m = 32; m >= 1; m >>= 1) acc += __shfl_xor(acc, m);
    if (lane == 0) y[gw] = acc + fb[o];
}

extern "C" void kernel_launch(void* const* d_in, const int* in_sizes, int n_in,
                              void* d_out, int out_size, void* d_ws, size_t ws_size,
                              hipStream_t stream)
{
    (void)in_sizes; (void)n_in; (void)out_size; (void)ws_size;
    const float* x   = (const float*)d_in[0];
    const float* s1w0 = (const float*)d_in[1];  const float* s1b0 = (const float*)d_in[2];
    const float* s1w1 = (const float*)d_in[3];  const float* s1b1 = (const float*)d_in[4];
    const float* s1w2 = (const float*)d_in[5];  const float* s1b2 = (const float*)d_in[6];
    const float* s2w0 = (const float*)d_in[7];  const float* s2b0 = (const float*)d_in[8];
    const float* s2w1 = (const float*)d_in[9];  const float* s2b1 = (const float*)d_in[10];
    const float* s2w2 = (const float*)d_in[11]; const float* s2b2 = (const float*)d_in[12];
    const float* s3w0 = (const float*)d_in[13]; const float* s3b0 = (const float*)d_in[14];
    const float* s3w1 = (const float*)d_in[15]; const float* s3b1 = (const float*)d_in[16];
    const float* s3w2 = (const float*)d_in[17]; const float* s3b2 = (const float*)d_in[18];
    const float* fw  = (const float*)d_in[19]; const float* fb  = (const float*)d_in[20];
    float* y = (float*)d_out;

    char* ws = (char*)d_ws;
    float* l1_xyz = (float*)(ws + 0);          // 16*512*3
    int*   idx1   = (int*)  (ws + 98304);      // 16*512*32
    float* l1_pts = (float*)(ws + 1146880);    // 16*512*128
    float* l2_xyz = (float*)(ws + 5341184);    // 16*128*3
    int*   idx2   = (int*)  (ws + 5365760);    // 16*128*64
    float* l2_pts = (float*)(ws + 5890048);    // 16*128*256
    float* h1     = (float*)(ws + 7987200);    // 2048*256
    float* h2     = (float*)(ws + 10084352);   // 2048*512
    float* pmax   = (float*)(ws + 14278656);   // 32*1024 partial maxes
    float* wt1_0  = (float*)(ws + 14409728);   // [3][64]
    float* wt1_1  = (float*)(ws + 14410496);   // [64][64]
    float* wt1_2  = (float*)(ws + 14426880);   // [64][128]
    float* wt2_0  = (float*)(ws + 14459648);   // [131][128]
    float* wt2_1  = (float*)(ws + 14526720);   // [128][128]
    float* wt2_2  = (float*)(ws + 14592256);   // [128][256]
    float* wt3_0  = (float*)(ws + 14723328);   // [259][256]
    float* wt3_1  = (float*)(ws + 14988544);   // [256][512]
    float* wt3_2  = (float*)(ws + 15512832);   // [512][1024]

    const float r2_1 = (float)(0.2 * 0.2);
    const float r2_2 = (float)(0.4 * 0.4);

    transpose_all<<<3126, 256, 0, stream>>>(
        s1w0, wt1_0, s1w1, wt1_1, s1w2, wt1_2,
        s2w0, wt2_0, s2w1, wt2_1, s2w2, wt2_2,
        s3w0, wt3_0, s3w1, wt3_1, s3w2, wt3_2);

    fps_fused<4096, 512, 128, 512><<<BATCH, 512, 0, stream>>>(x, l1_xyz, l2_xyz);
    ballq_kernel<4096, 512, 32><<<(BATCH*512)/4, 256, 0, stream>>>(x, l1_xyz, idx1, r2_1);
    sa1_fused<<<(BATCH*512*32)/64, 256, 0, stream>>>(x, l1_xyz, idx1,
        wt1_0, s1b0, wt1_1, s1b1, wt1_2, s1b2, l1_pts);
    ballq_kernel<512, 128, 64><<<(BATCH*128)/4, 256, 0, stream>>>(l1_xyz, l2_xyz, idx2, r2_2);
    sa2_fused<<<BATCH*128, 256, 0, stream>>>(l1_xyz, l1_pts, l2_xyz, idx2,
        wt2_0, s2b0, wt2_1, s2b1, wt2_2, s2b2, l2_pts);
    mlp_gemm_kernel<259, 256,  true,  false><<<dim3(32, 4),  256, 0, stream>>>(l2_xyz, l2_pts, wt3_0, s3b0, h1);
    mlp_gemm_kernel<256, 512,  false, false><<<dim3(32, 8),  256, 0, stream>>>(h1, nullptr, wt3_1, s3b1, h2);
    mlp_gemm_kernel<512, 1024, false, true ><<<dim3(32, 16), 256, 0, stream>>>(h2, nullptr, wt3_2, s3b2, pmax);
    fc_kernel<<<(BATCH*1024)/4, 256, 0, stream>>>(pmax, fw, fb, y);
}

// Round 6
// 1115.742 us; speedup vs baseline: 2.8685x; 1.0856x over previous
//
#include <hip/hip_runtime.h>

#ifndef BATCH
#define BATCH 16
#endif

// ---- DPP wave64 reduction helpers (row_shr scan + row_bcast merge) --------
template<int CTRL>
__device__ __forceinline__ float dppmaxf(float v)
{
    const int d = __builtin_amdgcn_update_dpp(__float_as_int(v), __float_as_int(v),
                                              CTRL, 0xf, 0xf, false);
    return fmaxf(v, __int_as_float(d));
}
template<int CTRL>
__device__ __forceinline__ unsigned dppminu(unsigned v)
{
    const unsigned d = (unsigned)__builtin_amdgcn_update_dpp((int)v, (int)v,
                                                             CTRL, 0xf, 0xf, false);
    return (d < v) ? d : v;
}
// full-wave max of v -> wave-uniform result (via lane 63)
__device__ __forceinline__ float wave_max_bcast(float v)
{
    v = dppmaxf<0x111>(v);  // row_shr:1
    v = dppmaxf<0x112>(v);  // row_shr:2
    v = dppmaxf<0x114>(v);  // row_shr:4
    v = dppmaxf<0x118>(v);  // row_shr:8
    v = dppmaxf<0x142>(v);  // row_bcast:15
    v = dppmaxf<0x143>(v);  // row_bcast:31
    return __int_as_float(__builtin_amdgcn_readlane(__float_as_int(v), 63));
}
__device__ __forceinline__ unsigned wave_min_bcast(unsigned v)
{
    v = dppminu<0x111>(v);
    v = dppminu<0x112>(v);
    v = dppminu<0x114>(v);
    v = dppminu<0x118>(v);
    v = dppminu<0x142>(v);
    v = dppminu<0x143>(v);
    return (unsigned)__builtin_amdgcn_readlane((int)v, 63);
}

// ---------------------------------------------------------------------------
// Fused FPS (both stages). One block per batch, BLOCK=256 (1 wave/SIMD).
// Per step: dist update (P pts/thread), DPP value-max + index-min reduce,
// one LDS atomicMax per wave into 3-slot rotation, one barrier.
// Bit-exact: contract(off), (dx*dx+dy*dy)+dz*dz, strict-> first-index argmax.
// ---------------------------------------------------------------------------
template<int N, int NP1, int NP2, int BLOCK>
__global__ __launch_bounds__(BLOCK)
void fps_fused(const float* __restrict__ xyz,
               float* __restrict__ out1, float* __restrict__ out2)
{
#pragma clang fp contract(off)
    constexpr int P  = N / BLOCK;     // stage-1 points per thread
    constexpr int P2 = NP1 / BLOCK;   // stage-2 points per thread
    __shared__ float sx[N], sy[N], sz[N];
    __shared__ float s2x[NP1], s2y[NP1], s2z[NP1];
    __shared__ unsigned long long slot[3];
    const int b = blockIdx.x, t = threadIdx.x;
    const float* xb = xyz + (size_t)b * N * 3;
    float px[P], py[P], pz[P], dist[P];
#pragma unroll
    for (int j = 0; j < P; ++j) {
        const int i = t + j * BLOCK;
        const float x = xb[i*3+0], y = xb[i*3+1], z = xb[i*3+2];
        sx[i] = x; sy[i] = y; sz[i] = z;
        px[j] = x; py[j] = y; pz[j] = z;
        dist[j] = 1e10f;
    }
    if (t < 3) slot[t] = 0ull;
    __syncthreads();
    int far = 0;
    if (t == 0) {
        out1[(size_t)b*NP1*3 + 0] = sx[0];
        out1[(size_t)b*NP1*3 + 1] = sy[0];
        out1[(size_t)b*NP1*3 + 2] = sz[0];
        s2x[0] = sx[0]; s2y[0] = sy[0]; s2z[0] = sz[0];
    }
    for (int s = 1; s < NP1; ++s) {
        const float fx = sx[far], fy = sy[far], fz = sz[far];
        float bestv = -1.f; int besti = 0;
#pragma unroll
        for (int j = 0; j < P; ++j) {
            const float dx = px[j]-fx, dy = py[j]-fy, dz = pz[j]-fz;
            const float d = (dx*dx + dy*dy) + dz*dz;
            const float nd = fminf(dist[j], d);
            dist[j] = nd;
            if (nd > bestv) { bestv = nd; besti = t + j * BLOCK; }  // first idx kept
        }
        const float wm = wave_max_bcast(bestv);
        const unsigned cand = (bestv == wm) ? (unsigned)besti : 0xffffffffu;
        const unsigned wi = wave_min_bcast(cand);
        if ((t & 63) == 0) {
            const unsigned long long pk =
                ((unsigned long long)__float_as_uint(wm) << 32) | (unsigned)(~wi);
            atomicMax(&slot[s % 3], pk);
        }
        if (t == 0) slot[(s + 1) % 3] = 0ull;   // safe: last read 2 steps ago
        __syncthreads();
        far = (int)(~(unsigned)slot[s % 3]);
        if (t == 0) {
            const float X = sx[far], Y = sy[far], Z = sz[far];
            out1[((size_t)b*NP1 + s)*3 + 0] = X;
            out1[((size_t)b*NP1 + s)*3 + 1] = Y;
            out1[((size_t)b*NP1 + s)*3 + 2] = Z;
            s2x[s] = X; s2y[s] = Y; s2z[s] = Z;
        }
    }
    __syncthreads();             // s2 arrays complete
    if (t < 3) slot[t] = 0ull;   // clear rotation for stage 2
    __syncthreads();
    // -------- stage 2: FPS over NP1 sampled points (P2 per thread) ----------
    float mx[P2], my[P2], mz[P2], d2[P2];
#pragma unroll
    for (int j = 0; j < P2; ++j) {
        const int i = t + j * BLOCK;
        mx[j] = s2x[i]; my[j] = s2y[i]; mz[j] = s2z[i];
        d2[j] = 1e10f;
    }
    int far2 = 0;
    if (t == 0) {
        out2[(size_t)b*NP2*3 + 0] = s2x[0];
        out2[(size_t)b*NP2*3 + 1] = s2y[0];
        out2[(size_t)b*NP2*3 + 2] = s2z[0];
    }
    for (int s = 1; s < NP2; ++s) {
        const float fx = s2x[far2], fy = s2y[far2], fz = s2z[far2];
        float bestv = -1.f; int besti = 0;
#pragma unroll
        for (int j = 0; j < P2; ++j) {
            const float dx = mx[j]-fx, dy = my[j]-fy, dz = mz[j]-fz;
            const float d = (dx*dx + dy*dy) + dz*dz;
            const float nd = fminf(d2[j], d);
            d2[j] = nd;
            if (nd > bestv) { bestv = nd; besti = t + j * BLOCK; }
        }
        const float wm = wave_max_bcast(bestv);
        const unsigned cand = (bestv == wm) ? (unsigned)besti : 0xffffffffu;
        const unsigned wi = wave_min_bcast(cand);
        if ((t & 63) == 0) {
            const unsigned long long pk =
                ((unsigned long long)__float_as_uint(wm) << 32) | (unsigned)(~wi);
            atomicMax(&slot[s % 3], pk);
        }
        if (t == 0) slot[(s + 1) % 3] = 0ull;
        __syncthreads();
        far2 = (int)(~(unsigned)slot[s % 3]);
        if (t == 0) {
            out2[((size_t)b*NP2 + s)*3 + 0] = s2x[far2];
            out2[((size_t)b*NP2 + s)*3 + 1] = s2y[far2];
            out2[((size_t)b*NP2 + s)*3 + 2] = s2z[far2];
        }
    }
}

// ---------------------------------------------------------------------------
// Ball query (unchanged, known-correct)
// ---------------------------------------------------------------------------
template<int N, int S, int K>
__global__ __launch_bounds__(256)
void ballq_kernel(const float* __restrict__ xyz, const float* __restrict__ nxyz,
                  int* __restrict__ idx, const float r2)
{
#pragma clang fp contract(off)
    const int gw = (blockIdx.x * 256 + threadIdx.x) >> 6;
    const int lane = threadIdx.x & 63;
    const int b = gw / S, s = gw % S;
    const float* xb = xyz + (size_t)b * N * 3;
    const float qx = nxyz[((size_t)b*S + s)*3 + 0];
    const float qy = nxyz[((size_t)b*S + s)*3 + 1];
    const float qz = nxyz[((size_t)b*S + s)*3 + 2];
    int* op = idx + ((size_t)b*S + s) * K;
    int base = 0, first = -1;
    for (int c = 0; c < N; c += 64) {
        const int i = c + lane;
        const float dx = xb[i*3+0]-qx, dy = xb[i*3+1]-qy, dz = xb[i*3+2]-qz;
        const float d = (dx*dx + dy*dy) + dz*dz;
        const bool hit = !(d > r2);
        const unsigned long long m = __ballot(hit);
        if (first < 0 && m) first = c + __builtin_ctzll(m);
        const int pos = base + __popcll(m & ((1ull << lane) - 1ull));
        if (hit && pos < K) op[pos] = i;
        base += __popcll(m);
        if (base >= K) break;
    }
    if (base < K && lane >= base && lane < K) op[lane] = first;
}

// ---------------------------------------------------------------------------
// All 9 weight transposes W[O][C] -> Wt[C][O] in one launch.
// ---------------------------------------------------------------------------
__global__ __launch_bounds__(256)
void transpose_all(const float* __restrict__ s0, float* __restrict__ d0,
                   const float* __restrict__ s1, float* __restrict__ d1,
                   const float* __restrict__ s2, float* __restrict__ d2,
                   const float* __restrict__ s3, float* __restrict__ d3,
                   const float* __restrict__ s4, float* __restrict__ d4,
                   const float* __restrict__ s5, float* __restrict__ d5,
                   const float* __restrict__ s6, float* __restrict__ d6,
                   const float* __restrict__ s7, float* __restrict__ d7,
                   const float* __restrict__ s8, float* __restrict__ d8)
{
    int i = blockIdx.x * 256 + threadIdx.x;
    if (i < 192)    { d0[(i%3)  *64   + i/3  ] = s0[i]; return; }  i -= 192;
    if (i < 4096)   { d1[(i&63) *64   + (i>>6)] = s1[i]; return; } i -= 4096;
    if (i < 8192)   { d2[(i&63) *128  + (i>>6)] = s2[i]; return; } i -= 8192;
    if (i < 16768)  { d3[(i%131)*128  + i/131] = s3[i]; return; }  i -= 16768;
    if (i < 16384)  { d4[(i&127)*128  + (i>>7)] = s4[i]; return; } i -= 16384;
    if (i < 32768)  { d5[(i&127)*256  + (i>>7)] = s5[i]; return; } i -= 32768;
    if (i < 66304)  { d6[(i%259)*256  + i/259] = s6[i]; return; }  i -= 66304;
    if (i < 131072) { d7[(i&255)*512  + (i>>8)] = s7[i]; return; } i -= 131072;
    if (i < 524288) { d8[(i&511)*1024 + (i>>9)] = s8[i]; return; }
}

// 16 FMAs against 16 contiguous transposed weights (4x float4, 16B-aligned)
__device__ __forceinline__ void fma16(float (&acc)[16], const float f,
                                      const float* __restrict__ wrow)
{
    const float4 w0 = ((const float4*)wrow)[0];
    const float4 w1 = ((const float4*)wrow)[1];
    const float4 w2 = ((const float4*)wrow)[2];
    const float4 w3 = ((const float4*)wrow)[3];
    acc[0]+=f*w0.x;  acc[1]+=f*w0.y;  acc[2]+=f*w0.z;  acc[3]+=f*w0.w;
    acc[4]+=f*w1.x;  acc[5]+=f*w1.y;  acc[6]+=f*w1.z;  acc[7]+=f*w1.w;
    acc[8]+=f*w2.x;  acc[9]+=f*w2.y;  acc[10]+=f*w2.z; acc[11]+=f*w2.w;
    acc[12]+=f*w3.x; acc[13]+=f*w3.y; acc[14]+=f*w3.z; acc[15]+=f*w3.w;
}

// ---------------------------------------------------------------------------
// SA1 fused (unchanged)
// ---------------------------------------------------------------------------
__global__ __launch_bounds__(256)
void sa1_fused(const float* __restrict__ xyz, const float* __restrict__ nxyz,
               const int* __restrict__ idx,
               const float* __restrict__ Wt0, const float* __restrict__ B0,
               const float* __restrict__ Wt1, const float* __restrict__ B1,
               const float* __restrict__ Wt2, const float* __restrict__ B2,
               float* __restrict__ out)
{
    __shared__ float h1S[64][64];
    __shared__ float h2S[64][64];
    const int tid = threadIdx.x, lane = tid & 63;
    const int wave = __builtin_amdgcn_readfirstlane(tid >> 6);
    const int row0 = blockIdx.x * 64;
    const int myrow = row0 + lane;
    const int g = myrow >> 5, b = g >> 9;
    const int i = idx[myrow];
    const float* p = xyz + ((size_t)b*4096 + i) * 3;
    const float f0 = p[0] - nxyz[(size_t)g*3 + 0];
    const float f1 = p[1] - nxyz[(size_t)g*3 + 1];
    const float f2 = p[2] - nxyz[(size_t)g*3 + 2];
    const int oc0 = wave * 16;
    float acc[16];
#pragma unroll
    for (int j = 0; j < 16; ++j)
        acc[j] = B0[oc0+j] + f0*Wt0[0*64+oc0+j] + f1*Wt0[1*64+oc0+j] + f2*Wt0[2*64+oc0+j];
#pragma unroll
    for (int j = 0; j < 16; ++j) h1S[oc0+j][lane] = fmaxf(acc[j], 0.f);
    __syncthreads();
#pragma unroll
    for (int j = 0; j < 16; ++j) acc[j] = B1[oc0+j];
#pragma unroll 4
    for (int ci = 0; ci < 64; ++ci)
        fma16(acc, h1S[ci][lane], Wt1 + ci*64 + oc0);
#pragma unroll
    for (int j = 0; j < 16; ++j) h2S[oc0+j][lane] = fmaxf(acc[j], 0.f);
    __syncthreads();
    for (int pass = 0; pass < 2; ++pass) {
        const int oc = pass*64 + oc0;
#pragma unroll
        for (int j = 0; j < 16; ++j) acc[j] = B2[oc+j];
#pragma unroll 4
        for (int ci = 0; ci < 64; ++ci)
            fma16(acc, h2S[ci][lane], Wt2 + ci*128 + oc);
#pragma unroll
        for (int j = 0; j < 16; ++j) {
            float v = fmaxf(acc[j], 0.f);
            v = fmaxf(v, __shfl_xor(v, 1));
            v = fmaxf(v, __shfl_xor(v, 2));
            v = fmaxf(v, __shfl_xor(v, 4));
            v = fmaxf(v, __shfl_xor(v, 8));
            v = fmaxf(v, __shfl_xor(v, 16));
            if ((lane & 31) == 0)
                out[(size_t)((row0 + lane) >> 5) * 128 + oc + j] = v;
        }
    }
}

// ---------------------------------------------------------------------------
// SA2 fused (unchanged)
// ---------------------------------------------------------------------------
__global__ __launch_bounds__(256)
void sa2_fused(const float* __restrict__ l1xyz, const float* __restrict__ l1pts,
               const float* __restrict__ nxyz, const int* __restrict__ idx,
               const float* __restrict__ Wt0, const float* __restrict__ B0,
               const float* __restrict__ Wt1, const float* __restrict__ B1,
               const float* __restrict__ Wt2, const float* __restrict__ B2,
               float* __restrict__ out)
{
    __shared__ float featS[128][64];
    __shared__ float hS[128][64];
    const int tid = threadIdx.x, lane = tid & 63;
    const int wave = __builtin_amdgcn_readfirstlane(tid >> 6);
    const int gblk = blockIdx.x;
    const int b = gblk >> 7;
    const int row0 = gblk * 64;
    const int myi = idx[row0 + lane];
    const float* pc = l1xyz + ((size_t)b*512 + myi) * 3;
    const float f0 = pc[0] - nxyz[(size_t)gblk*3 + 0];
    const float f1 = pc[1] - nxyz[(size_t)gblk*3 + 1];
    const float f2 = pc[2] - nxyz[(size_t)gblk*3 + 2];
    for (int r = wave; r < 64; r += 4) {
        const int i2 = idx[row0 + r];
        const float* src = l1pts + ((size_t)b*512 + i2) * 128;
        featS[lane][r ^ lane]    = src[lane];
        featS[lane+64][r ^ lane] = src[lane + 64];
    }
    __syncthreads();
    const int oc0 = wave * 16;
    float acc[16];
    for (int pass = 0; pass < 2; ++pass) {
        const int oc = pass*64 + oc0;
#pragma unroll
        for (int j = 0; j < 16; ++j)
            acc[j] = B0[oc+j] + f0*Wt0[0*128+oc+j] + f1*Wt0[1*128+oc+j] + f2*Wt0[2*128+oc+j];
#pragma unroll 4
        for (int ci = 0; ci < 128; ++ci)
            fma16(acc, featS[ci][lane ^ (ci & 63)], Wt0 + (size_t)(ci+3)*128 + oc);
#pragma unroll
        for (int j = 0; j < 16; ++j) hS[oc+j][lane] = fmaxf(acc[j], 0.f);
    }
    __syncthreads();
    for (int pass = 0; pass < 2; ++pass) {
        const int oc = pass*64 + oc0;
#pragma unroll
        for (int j = 0; j < 16; ++j) acc[j] = B1[oc+j];
#pragma unroll 4
        for (int ci = 0; ci < 128; ++ci)
            fma16(acc, hS[ci][lane], Wt1 + (size_t)ci*128 + oc);
#pragma unroll
        for (int j = 0; j < 16; ++j) featS[oc+j][lane] = fmaxf(acc[j], 0.f);
    }
    __syncthreads();
    float* orow = out + (size_t)gblk * 256;
    for (int pass = 0; pass < 4; ++pass) {
        const int oc = pass*64 + oc0;
#pragma unroll
        for (int j = 0; j < 16; ++j) acc[j] = B2[oc+j];
#pragma unroll 4
        for (int ci = 0; ci < 128; ++ci)
            fma16(acc, featS[ci][lane], Wt2 + (size_t)ci*256 + oc);
#pragma unroll
        for (int j = 0; j < 16; ++j) {
            float v = fmaxf(acc[j], 0.f);
            v = fmaxf(v, __shfl_xor(v, 1));
            v = fmaxf(v, __shfl_xor(v, 2));
            v = fmaxf(v, __shfl_xor(v, 4));
            v = fmaxf(v, __shfl_xor(v, 8));
            v = fmaxf(v, __shfl_xor(v, 16));
            v = fmaxf(v, __shfl_xor(v, 32));
            if (lane == 0) orow[oc + j] = v;
        }
    }
}

// ---------------------------------------------------------------------------
// SA3 GEMM layers (unchanged)
// ---------------------------------------------------------------------------
template<int CIN, int COUT, bool CONCAT3, bool POOL>
__global__ __launch_bounds__(256)
void mlp_gemm_kernel(const float* __restrict__ inA, const float* __restrict__ inB,
                     const float* __restrict__ Wt, const float* __restrict__ Bb,
                     float* __restrict__ out)
{
    __shared__ float featS[128][64];
    const int tid = threadIdx.x, lane = tid & 63;
    const int wave = __builtin_amdgcn_readfirstlane(tid >> 6);
    const int row0 = blockIdx.x * 64;
    const int oc0 = blockIdx.y * 64 + wave * 16;
    float acc[16];
#pragma unroll
    for (int j = 0; j < 16; ++j) acc[j] = Bb[oc0 + j];
    for (int c0 = 0; c0 < CIN; c0 += 128) {
        const int csz = (CIN - c0 < 128) ? (CIN - c0) : 128;
        __syncthreads();
        for (int r = wave; r < 64; r += 4) {
            const int row = row0 + r;
            for (int cl = lane; cl < csz; cl += 64) {
                const int cig = c0 + cl;
                float v;
                if (CONCAT3)
                    v = (cig < 3) ? inA[(size_t)row*3 + cig]
                                  : inB[(size_t)row*(CIN-3) + (cig - 3)];
                else
                    v = inA[(size_t)row*CIN + cig];
                featS[cl][r ^ (cl & 63)] = v;
            }
        }
        __syncthreads();
        if (csz == 128) {
#pragma unroll 4
            for (int ci = 0; ci < 128; ++ci)
                fma16(acc, featS[ci][lane ^ (ci & 63)], Wt + (size_t)(c0+ci)*COUT + oc0);
        } else {
            for (int ci = 0; ci < csz; ++ci)
                fma16(acc, featS[ci][lane ^ (ci & 63)], Wt + (size_t)(c0+ci)*COUT + oc0);
        }
    }
    if (POOL) {
#pragma unroll
        for (int j = 0; j < 16; ++j) {
            float v = fmaxf(acc[j], 0.f);
            v = fmaxf(v, __shfl_xor(v, 1));
            v = fmaxf(v, __shfl_xor(v, 2));
            v = fmaxf(v, __shfl_xor(v, 4));
            v = fmaxf(v, __shfl_xor(v, 8));
            v = fmaxf(v, __shfl_xor(v, 16));
            v = fmaxf(v, __shfl_xor(v, 32));
            if (lane == 0) out[(size_t)blockIdx.x * COUT + oc0 + j] = v;
        }
    } else {
        float4 o0, o1, o2, o3;
        o0.x=fmaxf(acc[0],0.f);  o0.y=fmaxf(acc[1],0.f);  o0.z=fmaxf(acc[2],0.f);  o0.w=fmaxf(acc[3],0.f);
        o1.x=fmaxf(acc[4],0.f);  o1.y=fmaxf(acc[5],0.f);  o1.z=fmaxf(acc[6],0.f);  o1.w=fmaxf(acc[7],0.f);
        o2.x=fmaxf(acc[8],0.f);  o2.y=fmaxf(acc[9],0.f);  o2.z=fmaxf(acc[10],0.f); o2.w=fmaxf(acc[11],0.f);
        o3.x=fmaxf(acc[12],0.f); o3.y=fmaxf(acc[13],0.f); o3.z=fmaxf(acc[14],0.f); o3.w=fmaxf(acc[15],0.f);
        float4* op = (float4*)(out + (size_t)(row0 + lane)*COUT + oc0);
        op[0]=o0; op[1]=o1; op[2]=o2; op[3]=o3;
    }
}

// y[b][o] = fb[o] + max(pmax[2b], pmax[2b+1]) . fw[o]; one wave per output
__global__ __launch_bounds__(256)
void fc_kernel(const float* __restrict__ pmax, const float* __restrict__ fw,
               const float* __restrict__ fb, float* __restrict__ y)
{
    const int gw = (blockIdx.x * 256 + threadIdx.x) >> 6;
    const int lane = threadIdx.x & 63;
    const int b = gw >> 10, o = gw & 1023;
    const float4* g0 = (const float4*)(pmax + (size_t)(2*b) * 1024);
    const float4* g1 = (const float4*)(pmax + (size_t)(2*b+1) * 1024);
    const float4* wv = (const float4*)(fw + (size_t)o * 1024);
    float acc = 0.f;
#pragma unroll
    for (int r = 0; r < 4; ++r) {
        const float4 a = g0[lane + r*64];
        const float4 c = g1[lane + r*64];
        const float4 w = wv[lane + r*64];
        acc += fmaxf(a.x,c.x)*w.x + fmaxf(a.y,c.y)*w.y
             + fmaxf(a.z,c.z)*w.z + fmaxf(a.w,c.w)*w.w;
    }
#pragma unroll
    for (int m = 32; m >= 1; m >>= 1) acc += __shfl_xor(acc, m);
    if (lane == 0) y[gw] = acc + fb[o];
}

extern "C" void kernel_launch(void* const* d_in, const int* in_sizes, int n_in,
                              void* d_out, int out_size, void* d_ws, size_t ws_size,
                              hipStream_t stream)
{
    (void)in_sizes; (void)n_in; (void)out_size; (void)ws_size;
    const float* x   = (const float*)d_in[0];
    const float* s1w0 = (const float*)d_in[1];  const float* s1b0 = (const float*)d_in[2];
    const float* s1w1 = (const float*)d_in[3];  const float* s1b1 = (const float*)d_in[4];
    const float* s1w2 = (const float*)d_in[5];  const float* s1b2 = (const float*)d_in[6];
    const float* s2w0 = (const float*)d_in[7];  const float* s2b0 = (const float*)d_in[8];
    const float* s2w1 = (const float*)d_in[9];  const float* s2b1 = (const float*)d_in[10];
    const float* s2w2 = (const float*)d_in[11]; const float* s2b2 = (const float*)d_in[12];
    const float* s3w0 = (const float*)d_in[13]; const float* s3b0 = (const float*)d_in[14];
    const float* s3w1 = (const float*)d_in[15]; const float* s3b1 = (const float*)d_in[16];
    const float* s3w2 = (const float*)d_in[17]; const float* s3b2 = (const float*)d_in[18];
    const float* fw  = (const float*)d_in[19]; const float* fb  = (const float*)d_in[20];
    float* y = (float*)d_out;

    char* ws = (char*)d_ws;
    float* l1_xyz = (float*)(ws + 0);          // 16*512*3
    int*   idx1   = (int*)  (ws + 98304);      // 16*512*32
    float* l1_pts = (float*)(ws + 1146880);    // 16*512*128
    float* l2_xyz = (float*)(ws + 5341184);    // 16*128*3
    int*   idx2   = (int*)  (ws + 5365760);    // 16*128*64
    float* l2_pts = (float*)(ws + 5890048);    // 16*128*256
    float* h1     = (float*)(ws + 7987200);    // 2048*256
    float* h2     = (float*)(ws + 10084352);   // 2048*512
    float* pmax   = (float*)(ws + 14278656);   // 32*1024 partial maxes
    float* wt1_0  = (float*)(ws + 14409728);   // [3][64]
    float* wt1_1  = (float*)(ws + 14410496);   // [64][64]
    float* wt1_2  = (float*)(ws + 14426880);   // [64][128]
    float* wt2_0  = (float*)(ws + 14459648);   // [131][128]
    float* wt2_1  = (float*)(ws + 14526720);   // [128][128]
    float* wt2_2  = (float*)(ws + 14592256);   // [128][256]
    float* wt3_0  = (float*)(ws + 14723328);   // [259][256]
    float* wt3_1  = (float*)(ws + 14988544);   // [256][512]
    float* wt3_2  = (float*)(ws + 15512832);   // [512][1024]

    const float r2_1 = (float)(0.2 * 0.2);
    const float r2_2 = (float)(0.4 * 0.4);

    transpose_all<<<3126, 256, 0, stream>>>(
        s1w0, wt1_0, s1w1, wt1_1, s1w2, wt1_2,
        s2w0, wt2_0, s2w1, wt2_1, s2w2, wt2_2,
        s3w0, wt3_0, s3w1, wt3_1, s3w2, wt3_2);

    fps_fused<4096, 512, 128, 256><<<BATCH, 256, 0, stream>>>(x, l1_xyz, l2_xyz);
    ballq_kernel<4096, 512, 32><<<(BATCH*512)/4, 256, 0, stream>>>(x, l1_xyz, idx1, r2_1);
    sa1_fused<<<(BATCH*512*32)/64, 256, 0, stream>>>(x, l1_xyz, idx1,
        wt1_0, s1b0, wt1_1, s1b1, wt1_2, s1b2, l1_pts);
    ballq_kernel<512, 128, 64><<<(BATCH*128)/4, 256, 0, stream>>>(l1_xyz, l2_xyz, idx2, r2_2);
    sa2_fused<<<BATCH*128, 256, 0, stream>>>(l1_xyz, l1_pts, l2_xyz, idx2,
        wt2_0, s2b0, wt2_1, s2b1, wt2_2, s2b2, l2_pts);
    mlp_gemm_kernel<259, 256,  true,  false><<<dim3(32, 4),  256, 0, stream>>>(l2_xyz, l2_pts, wt3_0, s3b0, h1);
    mlp_gemm_kernel<256, 512,  false, false><<<dim3(32, 8),  256, 0, stream>>>(h1, nullptr, wt3_1, s3b1, h2);
    mlp_gemm_kernel<512, 1024, false, true ><<<dim3(32, 16), 256, 0, stream>>>(h2, nullptr, wt3_2, s3b2, pmax);
    fc_kernel<<<(BATCH*1024)/4, 256, 0, stream>>>(pmax, fw, fb, y);
}